// Round 1
// baseline (1149.676 us; speedup 1.0000x reference)
//
#include <hip/hip_runtime.h>
#include <hip/hip_bf16.h>

#define HH_ 80
#define WW_ 80
#define CIN_ 256
#define NF_ 128
#define NPIX_ 6400
#define NTOK_ 12800
#define NELEM_ (NTOK_ * NF_)       // 1,638,400
#define NXEL_  (NTOK_ * CIN_)      // 3,276,800
#define KW_    2304                // 9*256  (conv3 K)
#define KWC_   1152                // 9*128  (conv_out K)
#define WEL_   294912

// fp32 conv outputs (consumed by prep_pack)
__device__ float g_theta[NELEM_];
__device__ float g_phi  [NELEM_];
__device__ float g_gv   [NELEM_];
// bf16 attention output (consumed by conv_out_mfma)
__device__ unsigned short g_aob[NELEM_];
// bf16 MFMA operands for attention
__device__ unsigned short g_th_hi[NELEM_], g_th_lo[NELEM_];
__device__ unsigned short g_phT_hi[NELEM_], g_phT_lo[NELEM_];
__device__ unsigned short g_gT[NELEM_];
// bf16 hi/lo split of x, and transposed bf16 weights [f][k]
__device__ unsigned short g_xh[NXEL_], g_xl[NXEL_];
__device__ unsigned short g_wtTh[WEL_], g_wtTl[WEL_];
__device__ unsigned short g_wpTh[WEL_], g_wpTl[WEL_];
__device__ unsigned short g_wgT[WEL_];
__device__ unsigned short g_wcT[WEL_];

__device__ __forceinline__ float b2f(unsigned short u) {
    union { unsigned int i; float f; } v; v.i = ((unsigned int)u) << 16; return v.f;
}
__device__ __forceinline__ unsigned short f2b(float f) {
    union { float f; unsigned int i; } v; v.f = f;
    unsigned int i = v.i;
    i += 0x7fffu + ((i >> 16) & 1u);   // RNE (finite only)
    return (unsigned short)(i >> 16);
}

typedef __attribute__((ext_vector_type(8))) short bf16x8;
typedef __attribute__((ext_vector_type(4))) float f32x4;

__device__ __forceinline__ f32x4 mfma16(bf16x8 a, bf16x8 b, f32x4 c) {
    return __builtin_amdgcn_mfma_f32_16x16x32_bf16(a, b, c, 0, 0, 0);
}

// ---------------------------------------------------------------------------
// prep_x: fp32 x -> bf16 hi/lo split
// ---------------------------------------------------------------------------
__global__ __launch_bounds__(256) void prep_x(const float* __restrict__ x)
{
    const int i = (blockIdx.x * 256 + threadIdx.x) * 4;
    if (i >= NXEL_) return;
    const float4 v = *(const float4*)(x + i);
    ushort4 hi, lo;
    hi.x = f2b(v.x); lo.x = f2b(v.x - b2f(hi.x));
    hi.y = f2b(v.y); lo.y = f2b(v.y - b2f(hi.y));
    hi.z = f2b(v.z); lo.z = f2b(v.z - b2f(hi.z));
    hi.w = f2b(v.w); lo.w = f2b(v.w - b2f(hi.w));
    *(ushort4*)(g_xh + i) = hi;
    *(ushort4*)(g_xl + i) = lo;
}

// ---------------------------------------------------------------------------
// prep_w: transpose HWIO weights to [f][k] bf16 (hi/lo for w_theta/w_phi)
// ---------------------------------------------------------------------------
__global__ __launch_bounds__(256) void prep_w(
    const float* __restrict__ wt, const float* __restrict__ wp,
    const float* __restrict__ wg, const float* __restrict__ wc)
{
    const int i = blockIdx.x * 256 + threadIdx.x;
    if (i >= WEL_) return;
    {
        const int t  = i / (256 * 128);
        const int r  = i % (256 * 128);
        const int ci = r >> 7;
        const int f  = r & 127;
        const size_t d = (size_t)f * KW_ + t * 256 + ci;
        const float tv = wt[i];
        const unsigned short th = f2b(tv);
        g_wtTh[d] = th; g_wtTl[d] = f2b(tv - b2f(th));
        const float pv = wp[i];
        const unsigned short ph = f2b(pv);
        g_wpTh[d] = ph; g_wpTl[d] = f2b(pv - b2f(ph));
        g_wgT[d] = f2b(wg[i]);
    }
    {
        const int t  = i / (128 * 256);
        const int r  = i % (128 * 256);
        const int ci = r >> 8;
        const int f  = r & 255;
        g_wcT[(size_t)f * KWC_ + t * 128 + ci] = f2b(wc[i]);
    }
}

// ---------------------------------------------------------------------------
// conv3_mfma: implicit-GEMM 3x3 conv, 3 heads fused (r15, verified).
// ---------------------------------------------------------------------------
__global__ __launch_bounds__(256) void conv3_mfma()
{
    const int tid = threadIdx.x;
    const int w = tid >> 6, lane = tid & 63, quad = lane >> 4, ll = lane & 15;
    const int P0 = blockIdx.x * 32;
    const int fb = w * 32;

    int pb[2], ph[2], pw[2];
    #pragma unroll
    for (int pt = 0; pt < 2; ++pt) {
        const int p = P0 + pt * 16 + ll;
        pb[pt] = p / NPIX_;
        const int pl_ = p % NPIX_;
        ph[pt] = pl_ / WW_;
        pw[pt] = pl_ % WW_;
    }

    const bf16x8 ZV = {0,0,0,0,0,0,0,0};
    f32x4 aT[2][2], aP[2][2], aG[2][2];
    #pragma unroll
    for (int pt = 0; pt < 2; ++pt)
        #pragma unroll
        for (int ft = 0; ft < 2; ++ft) {
            aT[pt][ft] = (f32x4){0.f,0.f,0.f,0.f};
            aP[pt][ft] = (f32x4){0.f,0.f,0.f,0.f};
            aG[pt][ft] = (f32x4){0.f,0.f,0.f,0.f};
        }

    for (int t = 0; t < 9; ++t) {
        const int dh = t / 3 - 1, dw = t % 3 - 1;
        size_t abase[2]; bool av[2];
        #pragma unroll
        for (int pt = 0; pt < 2; ++pt) {
            const int hh = ph[pt] + dh, ww2 = pw[pt] + dw;
            av[pt] = (hh >= 0 && hh < HH_ && ww2 >= 0 && ww2 < WW_);
            abase[pt] = ((size_t)pb[pt] * NPIX_ + hh * WW_ + ww2) * CIN_;
        }
        const int wkb = t * 256;
        for (int kc = 0; kc < 8; ++kc) {
            const int ko = kc * 32 + quad * 8;
            bf16x8 aH[2], aL[2];
            #pragma unroll
            for (int pt = 0; pt < 2; ++pt) {
                if (av[pt]) {
                    aH[pt] = *(const bf16x8*)(g_xh + abase[pt] + ko);
                    aL[pt] = *(const bf16x8*)(g_xl + abase[pt] + ko);
                } else { aH[pt] = ZV; aL[pt] = ZV; }
            }
            const int wk = wkb + ko;
            #pragma unroll
            for (int ft = 0; ft < 2; ++ft) {
                const size_t wo = (size_t)(fb + ft * 16 + ll) * KW_ + wk;
                const bf16x8 tH = *(const bf16x8*)(g_wtTh + wo);
                const bf16x8 tL = *(const bf16x8*)(g_wtTl + wo);
                const bf16x8 pH = *(const bf16x8*)(g_wpTh + wo);
                const bf16x8 pL = *(const bf16x8*)(g_wpTl + wo);
                const bf16x8 gB = *(const bf16x8*)(g_wgT + wo);
                #pragma unroll
                for (int pt = 0; pt < 2; ++pt) {
                    aT[pt][ft] = mfma16(aH[pt], tH, aT[pt][ft]);
                    aT[pt][ft] = mfma16(aH[pt], tL, aT[pt][ft]);
                    aT[pt][ft] = mfma16(aL[pt], tH, aT[pt][ft]);
                    aP[pt][ft] = mfma16(aH[pt], pH, aP[pt][ft]);
                    aP[pt][ft] = mfma16(aH[pt], pL, aP[pt][ft]);
                    aP[pt][ft] = mfma16(aL[pt], pH, aP[pt][ft]);
                    aG[pt][ft] = mfma16(aH[pt], gB, aG[pt][ft]);
                }
            }
        }
    }

    #pragma unroll
    for (int pt = 0; pt < 2; ++pt)
        #pragma unroll
        for (int ft = 0; ft < 2; ++ft) {
            const int f = fb + ft * 16 + ll;
            #pragma unroll
            for (int r = 0; r < 4; ++r) {
                const size_t n = P0 + pt * 16 + quad * 4 + r;
                g_theta[n * NF_ + f] = aT[pt][ft][r];
                g_phi  [n * NF_ + f] = aP[pt][ft][r];
                g_gv   [n * NF_ + f] = aG[pt][ft][r];
            }
        }
}

// ---------------------------------------------------------------------------
// prep_pack (r14, verified)
// ---------------------------------------------------------------------------
__global__ __launch_bounds__(256) void prep_pack()
{
    const int i = blockIdx.x * 256 + threadIdx.x;
    if (i >= NELEM_) return;
    const int n  = i >> 7;
    const int c  = i & 127;
    const int b  = n / NPIX_;
    const int nl = n % NPIX_;

    const float tv = g_theta[i];
    const unsigned short th = f2b(tv);
    g_th_hi[i] = th;
    g_th_lo[i] = f2b(tv - b2f(th));

    const float pv = g_phi[i];
    const int j  = nl * 128 + c;
    const int cp = j / NPIX_;
    const int mp = j % NPIX_;
    const unsigned short phh = f2b(pv);
    const size_t o = (size_t)b * (NPIX_ * NF_) + (size_t)mp * 128 + cp;
    g_phT_hi[o] = phh;
    g_phT_lo[o] = f2b(pv - b2f(phh));

    g_gT[(size_t)b * (NPIX_ * NF_) + (size_t)c * NPIX_ + nl] = f2b(g_gv[i]);
}

// ---------------------------------------------------------------------------
// attn_mfma v3: 16 Q-rows/block, 4 waves, each wave owns all 16 rows and a
// 4-way split of m (64-m chunks, stride 256). Grid 800 (vs 400): the v2
// kernel was latency-bound at 17.5% occupancy (1.56 waves/SIMD, MfmaUtil
// 11.6% vs a ~40us MFMA issue floor at 297us). Halving rows/block halves
// LDS (54.3->27.1 KB) and VGPR state, doubling resident waves to
// ~3.1 waves/SIMD. Split-KV merge via bf16 O-partials in LDS. Per-wave
// P-LDS: no barrier in the K-loop.
// ---------------------------------------------------------------------------
__global__ __launch_bounds__(256, 4) void attn_mfma()
{
    __shared__ __align__(16) short p_lds[4][16 * 72];       // 9.2 KB
    __shared__ unsigned short o_lds[4][16][136];            // 17.4 KB (bf16)
    __shared__ float ml_lds[4][16][2];                      // 0.5 KB

    const int tid  = threadIdx.x;
    const int w    = tid >> 6;
    const int lane = tid & 63;
    const int quad = lane >> 4;
    const int ll   = lane & 15;
    const int R0   = blockIdx.x * 16;     // 16 | 6400 -> no batch straddle
    const int b    = R0 / NPIX_;

    const unsigned short* phH = g_phT_hi + (size_t)b * (NPIX_ * NF_);
    const unsigned short* phL = g_phT_lo + (size_t)b * (NPIX_ * NF_);
    const unsigned short* gT  = g_gT    + (size_t)b * (NPIX_ * NF_);

    // theta A-fragments: 1 row-tile x 4 k-steps x {hi,lo}
    bf16x8 aH[4], aL[4];
    #pragma unroll
    for (int kk = 0; kk < 4; ++kk) {
        const size_t off = (size_t)(R0 + ll) * 128 + kk * 32 + quad * 8;
        aH[kk] = *(const bf16x8*)(g_th_hi + off);
        aL[kk] = *(const bf16x8*)(g_th_lo + off);
    }

    f32x4 acc[8];
    #pragma unroll
    for (int t = 0; t < 8; ++t) acc[t] = (f32x4){0.f, 0.f, 0.f, 0.f};
    float mi[4], li[4];
    #pragma unroll
    for (int r = 0; r < 4; ++r) { mi[r] = -1e30f; li[r] = 0.f; }

    short* pl = &p_lds[w][0];

    for (int it = 0; it < 25; ++it) {
        const int m0 = it * 256 + w * 64;   // this wave's 64-m chunk

        // ---- S phase: 4 m-tiles x 4 k-steps, hi/lo split ------------------
        f32x4 s[4];
        #pragma unroll
        for (int mt = 0; mt < 4; ++mt) {
            f32x4 s0 = (f32x4){0.f,0.f,0.f,0.f};
            const int mm = m0 + mt * 16 + ll;
            #pragma unroll
            for (int kk = 0; kk < 4; ++kk) {
                const size_t off = (size_t)mm * 128 + kk * 32 + quad * 8;
                const bf16x8 bH = *(const bf16x8*)(phH + off);
                const bf16x8 bL = *(const bf16x8*)(phL + off);
                s0 = mfma16(aH[kk], bH, s0);
                s0 = mfma16(aH[kk], bL, s0);
                s0 = mfma16(aL[kk], bH, s0);
            }
            s[mt] = s0;
        }

        // ---- online softmax per row -----------------------------------------
        #pragma unroll
        for (int r = 0; r < 4; ++r) {
            float cm = fmaxf(fmaxf(s[0][r], s[1][r]),
                             fmaxf(s[2][r], s[3][r]));
            cm = fmaxf(cm, __shfl_xor(cm, 1));
            cm = fmaxf(cm, __shfl_xor(cm, 2));
            cm = fmaxf(cm, __shfl_xor(cm, 4));
            cm = fmaxf(cm, __shfl_xor(cm, 8));
            const float nm = fmaxf(mi[r], cm);
            const float al = __expf(mi[r] - nm);
            mi[r] = nm;
            float ssum = 0.f;
            #pragma unroll
            for (int mt = 0; mt < 4; ++mt) {
                const float e = __expf(s[mt][r] - nm);
                s[mt][r] = e; ssum += e;
            }
            ssum += __shfl_xor(ssum, 1);
            ssum += __shfl_xor(ssum, 2);
            ssum += __shfl_xor(ssum, 4);
            ssum += __shfl_xor(ssum, 8);
            li[r] = li[r] * al + ssum;
            #pragma unroll
            for (int t = 0; t < 8; ++t) acc[t][r] *= al;
        }

        // ---- P (C-layout) -> per-wave LDS [row][m] bf16 -> A-fragments -----
        #pragma unroll
        for (int mt = 0; mt < 4; ++mt)
            #pragma unroll
            for (int r = 0; r < 4; ++r)
                pl[(quad * 4 + r) * 72 + mt * 16 + ll] =
                    (short)f2b(s[mt][r]);
        bf16x8 pa[2];
        #pragma unroll
        for (int ks = 0; ks < 2; ++ks)
            pa[ks] = *(const bf16x8*)(pl + ll * 72 + ks * 32 + quad * 8);

        // ---- PV: 8 channel-tiles x 2 k-steps -------------------------------
        #pragma unroll
        for (int ct = 0; ct < 8; ++ct) {
            #pragma unroll
            for (int ks = 0; ks < 2; ++ks) {
                const bf16x8 gb = *(const bf16x8*)(
                    gT + (size_t)(ct * 16 + ll) * NPIX_ + m0 + ks * 32 + quad * 8);
                acc[ct] = mfma16(pa[ks], gb, acc[ct]);
            }
        }
    }

    // ---- split-KV merge across the 4 waves (bf16 partials) -----------------
    #pragma unroll
    for (int ct = 0; ct < 8; ++ct)
        #pragma unroll
        for (int r = 0; r < 4; ++r)
            o_lds[w][quad * 4 + r][ct * 16 + ll] = f2b(acc[ct][r]);
    if (ll == 0) {
        #pragma unroll
        for (int r = 0; r < 4; ++r) {
            ml_lds[w][quad * 4 + r][0] = mi[r];
            ml_lds[w][quad * 4 + r][1] = li[r];
        }
    }
    __syncthreads();

    const int n  = tid >> 4;           // 0..15
    const int c0 = (tid & 15) * 8;
    const float M = fmaxf(fmaxf(ml_lds[0][n][0], ml_lds[1][n][0]),
                          fmaxf(ml_lds[2][n][0], ml_lds[3][n][0]));
    float sc[4], L = 0.f;
    #pragma unroll
    for (int ww = 0; ww < 4; ++ww) {
        sc[ww] = __expf(ml_lds[ww][n][0] - M);
        L += ml_lds[ww][n][1] * sc[ww];
    }
    const float inv = 1.f / L;
    unsigned short tmp[8];
    #pragma unroll
    for (int j = 0; j < 8; ++j) {
        float o = 0.f;
        #pragma unroll
        for (int ww = 0; ww < 4; ++ww)
            o += b2f(o_lds[ww][n][c0 + j]) * sc[ww];
        tmp[j] = f2b(o * inv);
    }
    #pragma unroll
    for (int j = 0; j < 8; j += 4)
        *(ushort4*)(g_aob + (size_t)(R0 + n) * 128 + c0 + j) =
            make_ushort4(tmp[j], tmp[j+1], tmp[j+2], tmp[j+3]);
}

// ---------------------------------------------------------------------------
// conv_out_mfma: implicit-GEMM 3x3 conv (128->256, bf16) + fp32 residual
// ---------------------------------------------------------------------------
__global__ __launch_bounds__(256) void conv_out_mfma(
    const float* __restrict__ x, float* __restrict__ out)
{
    const int tid = threadIdx.x;
    const int w = tid >> 6, lane = tid & 63, quad = lane >> 4, ll = lane & 15;
    const int P0 = blockIdx.x * 32;
    const int fb = w * 64;

    int pb[2], ph[2], pw[2];
    #pragma unroll
    for (int pt = 0; pt < 2; ++pt) {
        const int p = P0 + pt * 16 + ll;
        pb[pt] = p / NPIX_;
        const int pl_ = p % NPIX_;
        ph[pt] = pl_ / WW_;
        pw[pt] = pl_ % WW_;
    }

    const bf16x8 ZV = {0,0,0,0,0,0,0,0};
    f32x4 acc[2][4];
    #pragma unroll
    for (int pt = 0; pt < 2; ++pt)
        #pragma unroll
        for (int ft = 0; ft < 4; ++ft) acc[pt][ft] = (f32x4){0.f,0.f,0.f,0.f};

    for (int t = 0; t < 9; ++t) {
        const int dh = t / 3 - 1, dw = t % 3 - 1;
        size_t abase[2]; bool av[2];
        #pragma unroll
        for (int pt = 0; pt < 2; ++pt) {
            const int hh = ph[pt] + dh, ww2 = pw[pt] + dw;
            av[pt] = (hh >= 0 && hh < HH_ && ww2 >= 0 && ww2 < WW_);
            abase[pt] = ((size_t)pb[pt] * NPIX_ + hh * WW_ + ww2) * NF_;
        }
        for (int kc = 0; kc < 4; ++kc) {
            const int ko = kc * 32 + quad * 8;
            bf16x8 a[2];
            #pragma unroll
            for (int pt = 0; pt < 2; ++pt)
                a[pt] = av[pt] ? *(const bf16x8*)(g_aob + abase[pt] + ko) : ZV;
            const int wk = t * 128 + ko;
            #pragma unroll
            for (int ft = 0; ft < 4; ++ft) {
                const bf16x8 bw = *(const bf16x8*)(
                    g_wcT + (size_t)(fb + ft * 16 + ll) * KWC_ + wk);
                #pragma unroll
                for (int pt = 0; pt < 2; ++pt)
                    acc[pt][ft] = mfma16(a[pt], bw, acc[pt][ft]);
            }
        }
    }

    #pragma unroll
    for (int pt = 0; pt < 2; ++pt)
        #pragma unroll
        for (int ft = 0; ft < 4; ++ft) {
            const int f = fb + ft * 16 + ll;
            #pragma unroll
            for (int r = 0; r < 4; ++r) {
                const size_t n = P0 + pt * 16 + quad * 4 + r;
                const size_t oi = n * CIN_ + f;
                out[oi] = x[oi] + acc[pt][ft][r];
            }
        }
}

// ---------------------------------------------------------------------------
extern "C" void kernel_launch(void* const* d_in, const int* in_sizes, int n_in,
                              void* d_out, int out_size, void* d_ws, size_t ws_size,
                              hipStream_t stream)
{
    const float* x  = (const float*)d_in[0];
    const float* wt = (const float*)d_in[1];
    const float* wp = (const float*)d_in[2];
    const float* wg = (const float*)d_in[3];
    const float* wc = (const float*)d_in[4];
    float* out = (float*)d_out;

    prep_x<<<NXEL_ / 4 / 256, 256, 0, stream>>>(x);
    prep_w<<<(WEL_ + 255) / 256, 256, 0, stream>>>(wt, wp, wg, wc);
    conv3_mfma<<<400, 256, 0, stream>>>();
    prep_pack<<<(NELEM_ + 255) / 256, 256, 0, stream>>>();
    attn_mfma<<<NTOK_ / 16, 256, 0, stream>>>();
    conv_out_mfma<<<400, 256, 0, stream>>>(x, out);
}

// Round 2
// 1016.650 us; speedup vs baseline: 1.1308x; 1.1308x over previous
//
#include <hip/hip_runtime.h>
#include <hip/hip_bf16.h>

#define HH_ 80
#define WW_ 80
#define CIN_ 256
#define NF_ 128
#define NPIX_ 6400
#define NTOK_ 12800
#define NELEM_ (NTOK_ * NF_)       // 1,638,400
#define NXEL_  (NTOK_ * CIN_)      // 3,276,800
#define KW_    2304                // 9*256  (conv3 K)
#define KWC_   1152                // 9*128  (conv_out K)
#define WEL_   294912

// fp32 conv outputs (consumed by prep_pack)
__device__ float g_theta[NELEM_];
__device__ float g_phi  [NELEM_];
__device__ float g_gv   [NELEM_];
// bf16 attention output (consumed by conv_out_mfma)
__device__ unsigned short g_aob[NELEM_];
// bf16 MFMA operands for attention
__device__ unsigned short g_th_hi[NELEM_], g_th_lo[NELEM_];
__device__ unsigned short g_phT_hi[NELEM_], g_phT_lo[NELEM_];
__device__ unsigned short g_gT[NELEM_];
// bf16 hi/lo split of x, and transposed bf16 weights [f][k]
__device__ unsigned short g_xh[NXEL_], g_xl[NXEL_];
__device__ unsigned short g_wtTh[WEL_], g_wtTl[WEL_];
__device__ unsigned short g_wpTh[WEL_], g_wpTl[WEL_];
__device__ unsigned short g_wgT[WEL_];
__device__ unsigned short g_wcT[WEL_];

__device__ __forceinline__ float b2f(unsigned short u) {
    union { unsigned int i; float f; } v; v.i = ((unsigned int)u) << 16; return v.f;
}
__device__ __forceinline__ unsigned short f2b(float f) {
    union { float f; unsigned int i; } v; v.f = f;
    unsigned int i = v.i;
    i += 0x7fffu + ((i >> 16) & 1u);   // RNE (finite only)
    return (unsigned short)(i >> 16);
}

typedef __attribute__((ext_vector_type(8))) short bf16x8;
typedef __attribute__((ext_vector_type(4))) float f32x4;

__device__ __forceinline__ f32x4 mfma16(bf16x8 a, bf16x8 b, f32x4 c) {
    return __builtin_amdgcn_mfma_f32_16x16x32_bf16(a, b, c, 0, 0, 0);
}

// ---------------------------------------------------------------------------
// prep_x: fp32 x -> bf16 hi/lo split
// ---------------------------------------------------------------------------
__global__ __launch_bounds__(256) void prep_x(const float* __restrict__ x)
{
    const int i = (blockIdx.x * 256 + threadIdx.x) * 4;
    if (i >= NXEL_) return;
    const float4 v = *(const float4*)(x + i);
    ushort4 hi, lo;
    hi.x = f2b(v.x); lo.x = f2b(v.x - b2f(hi.x));
    hi.y = f2b(v.y); lo.y = f2b(v.y - b2f(hi.y));
    hi.z = f2b(v.z); lo.z = f2b(v.z - b2f(hi.z));
    hi.w = f2b(v.w); lo.w = f2b(v.w - b2f(hi.w));
    *(ushort4*)(g_xh + i) = hi;
    *(ushort4*)(g_xl + i) = lo;
}

// ---------------------------------------------------------------------------
// prep_w: transpose HWIO weights to [f][k] bf16 (hi/lo for w_theta/w_phi)
// ---------------------------------------------------------------------------
__global__ __launch_bounds__(256) void prep_w(
    const float* __restrict__ wt, const float* __restrict__ wp,
    const float* __restrict__ wg, const float* __restrict__ wc)
{
    const int i = blockIdx.x * 256 + threadIdx.x;
    if (i >= WEL_) return;
    {
        const int t  = i / (256 * 128);
        const int r  = i % (256 * 128);
        const int ci = r >> 7;
        const int f  = r & 127;
        const size_t d = (size_t)f * KW_ + t * 256 + ci;
        const float tv = wt[i];
        const unsigned short th = f2b(tv);
        g_wtTh[d] = th; g_wtTl[d] = f2b(tv - b2f(th));
        const float pv = wp[i];
        const unsigned short ph = f2b(pv);
        g_wpTh[d] = ph; g_wpTl[d] = f2b(pv - b2f(ph));
        g_wgT[d] = f2b(wg[i]);
    }
    {
        const int t  = i / (128 * 256);
        const int r  = i % (128 * 256);
        const int ci = r >> 8;
        const int f  = r & 255;
        g_wcT[(size_t)f * KWC_ + t * 128 + ci] = f2b(wc[i]);
    }
}

// ---------------------------------------------------------------------------
// conv3_mfma: implicit-GEMM 3x3 conv, 3 heads fused (r15, verified).
// ---------------------------------------------------------------------------
__global__ __launch_bounds__(256) void conv3_mfma()
{
    const int tid = threadIdx.x;
    const int w = tid >> 6, lane = tid & 63, quad = lane >> 4, ll = lane & 15;
    const int P0 = blockIdx.x * 32;
    const int fb = w * 32;

    int pb[2], ph[2], pw[2];
    #pragma unroll
    for (int pt = 0; pt < 2; ++pt) {
        const int p = P0 + pt * 16 + ll;
        pb[pt] = p / NPIX_;
        const int pl_ = p % NPIX_;
        ph[pt] = pl_ / WW_;
        pw[pt] = pl_ % WW_;
    }

    const bf16x8 ZV = {0,0,0,0,0,0,0,0};
    f32x4 aT[2][2], aP[2][2], aG[2][2];
    #pragma unroll
    for (int pt = 0; pt < 2; ++pt)
        #pragma unroll
        for (int ft = 0; ft < 2; ++ft) {
            aT[pt][ft] = (f32x4){0.f,0.f,0.f,0.f};
            aP[pt][ft] = (f32x4){0.f,0.f,0.f,0.f};
            aG[pt][ft] = (f32x4){0.f,0.f,0.f,0.f};
        }

    for (int t = 0; t < 9; ++t) {
        const int dh = t / 3 - 1, dw = t % 3 - 1;
        size_t abase[2]; bool av[2];
        #pragma unroll
        for (int pt = 0; pt < 2; ++pt) {
            const int hh = ph[pt] + dh, ww2 = pw[pt] + dw;
            av[pt] = (hh >= 0 && hh < HH_ && ww2 >= 0 && ww2 < WW_);
            abase[pt] = ((size_t)pb[pt] * NPIX_ + hh * WW_ + ww2) * CIN_;
        }
        const int wkb = t * 256;
        for (int kc = 0; kc < 8; ++kc) {
            const int ko = kc * 32 + quad * 8;
            bf16x8 aH[2], aL[2];
            #pragma unroll
            for (int pt = 0; pt < 2; ++pt) {
                if (av[pt]) {
                    aH[pt] = *(const bf16x8*)(g_xh + abase[pt] + ko);
                    aL[pt] = *(const bf16x8*)(g_xl + abase[pt] + ko);
                } else { aH[pt] = ZV; aL[pt] = ZV; }
            }
            const int wk = wkb + ko;
            #pragma unroll
            for (int ft = 0; ft < 2; ++ft) {
                const size_t wo = (size_t)(fb + ft * 16 + ll) * KW_ + wk;
                const bf16x8 tH = *(const bf16x8*)(g_wtTh + wo);
                const bf16x8 tL = *(const bf16x8*)(g_wtTl + wo);
                const bf16x8 pH = *(const bf16x8*)(g_wpTh + wo);
                const bf16x8 pL = *(const bf16x8*)(g_wpTl + wo);
                const bf16x8 gB = *(const bf16x8*)(g_wgT + wo);
                #pragma unroll
                for (int pt = 0; pt < 2; ++pt) {
                    aT[pt][ft] = mfma16(aH[pt], tH, aT[pt][ft]);
                    aT[pt][ft] = mfma16(aH[pt], tL, aT[pt][ft]);
                    aT[pt][ft] = mfma16(aL[pt], tH, aT[pt][ft]);
                    aP[pt][ft] = mfma16(aH[pt], pH, aP[pt][ft]);
                    aP[pt][ft] = mfma16(aH[pt], pL, aP[pt][ft]);
                    aP[pt][ft] = mfma16(aL[pt], pH, aP[pt][ft]);
                    aG[pt][ft] = mfma16(aH[pt], gB, aG[pt][ft]);
                }
            }
        }
    }

    #pragma unroll
    for (int pt = 0; pt < 2; ++pt)
        #pragma unroll
        for (int ft = 0; ft < 2; ++ft) {
            const int f = fb + ft * 16 + ll;
            #pragma unroll
            for (int r = 0; r < 4; ++r) {
                const size_t n = P0 + pt * 16 + quad * 4 + r;
                g_theta[n * NF_ + f] = aT[pt][ft][r];
                g_phi  [n * NF_ + f] = aP[pt][ft][r];
                g_gv   [n * NF_ + f] = aG[pt][ft][r];
            }
        }
}

// ---------------------------------------------------------------------------
// prep_pack (r14, verified)
// ---------------------------------------------------------------------------
__global__ __launch_bounds__(256) void prep_pack()
{
    const int i = blockIdx.x * 256 + threadIdx.x;
    if (i >= NELEM_) return;
    const int n  = i >> 7;
    const int c  = i & 127;
    const int b  = n / NPIX_;
    const int nl = n % NPIX_;

    const float tv = g_theta[i];
    const unsigned short th = f2b(tv);
    g_th_hi[i] = th;
    g_th_lo[i] = f2b(tv - b2f(th));

    const float pv = g_phi[i];
    const int j  = nl * 128 + c;
    const int cp = j / NPIX_;
    const int mp = j % NPIX_;
    const unsigned short phh = f2b(pv);
    const size_t o = (size_t)b * (NPIX_ * NF_) + (size_t)mp * 128 + cp;
    g_phT_hi[o] = phh;
    g_phT_lo[o] = f2b(pv - b2f(phh));

    g_gT[(size_t)b * (NPIX_ * NF_) + (size_t)c * NPIX_ + nl] = f2b(g_gv[i]);
}

// ---------------------------------------------------------------------------
// attn_mfma v4: v3 structure (16 Q-rows/block, grid 800, 4-way m-split) with
// the register cap fixed. v3's __launch_bounds__(256,4) capped the unified
// VGPR+AGPR file at 128 -> acc[8]/aH/aL spilled to scratch (WRITE_SIZE
// 3.2 MB -> 667 MB, 775us). (256,3) caps at ~170 regs: the ~110-130 live
// state fits with zero spill, and if the allocator lands <=128 the HW can
// still co-schedule 4 waves/SIMD. LDS 27.1 KB. Per-wave P-LDS: no barrier
// in the K-loop.
// ---------------------------------------------------------------------------
__global__ __launch_bounds__(256, 3) void attn_mfma()
{
    __shared__ __align__(16) short p_lds[4][16 * 72];       // 9.2 KB
    __shared__ unsigned short o_lds[4][16][136];            // 17.4 KB (bf16)
    __shared__ float ml_lds[4][16][2];                      // 0.5 KB

    const int tid  = threadIdx.x;
    const int w    = tid >> 6;
    const int lane = tid & 63;
    const int quad = lane >> 4;
    const int ll   = lane & 15;
    const int R0   = blockIdx.x * 16;     // 16 | 6400 -> no batch straddle
    const int b    = R0 / NPIX_;

    const unsigned short* phH = g_phT_hi + (size_t)b * (NPIX_ * NF_);
    const unsigned short* phL = g_phT_lo + (size_t)b * (NPIX_ * NF_);
    const unsigned short* gT  = g_gT    + (size_t)b * (NPIX_ * NF_);

    // theta A-fragments: 1 row-tile x 4 k-steps x {hi,lo}
    bf16x8 aH[4], aL[4];
    #pragma unroll
    for (int kk = 0; kk < 4; ++kk) {
        const size_t off = (size_t)(R0 + ll) * 128 + kk * 32 + quad * 8;
        aH[kk] = *(const bf16x8*)(g_th_hi + off);
        aL[kk] = *(const bf16x8*)(g_th_lo + off);
    }

    f32x4 acc[8];
    #pragma unroll
    for (int t = 0; t < 8; ++t) acc[t] = (f32x4){0.f, 0.f, 0.f, 0.f};
    float mi[4], li[4];
    #pragma unroll
    for (int r = 0; r < 4; ++r) { mi[r] = -1e30f; li[r] = 0.f; }

    short* pl = &p_lds[w][0];

    for (int it = 0; it < 25; ++it) {
        const int m0 = it * 256 + w * 64;   // this wave's 64-m chunk

        // ---- S phase: 4 m-tiles x 4 k-steps, hi/lo split ------------------
        f32x4 s[4];
        #pragma unroll
        for (int mt = 0; mt < 4; ++mt) {
            f32x4 s0 = (f32x4){0.f,0.f,0.f,0.f};
            const int mm = m0 + mt * 16 + ll;
            #pragma unroll
            for (int kk = 0; kk < 4; ++kk) {
                const size_t off = (size_t)mm * 128 + kk * 32 + quad * 8;
                const bf16x8 bH = *(const bf16x8*)(phH + off);
                const bf16x8 bL = *(const bf16x8*)(phL + off);
                s0 = mfma16(aH[kk], bH, s0);
                s0 = mfma16(aH[kk], bL, s0);
                s0 = mfma16(aL[kk], bH, s0);
            }
            s[mt] = s0;
        }

        // ---- online softmax per row -----------------------------------------
        #pragma unroll
        for (int r = 0; r < 4; ++r) {
            float cm = fmaxf(fmaxf(s[0][r], s[1][r]),
                             fmaxf(s[2][r], s[3][r]));
            cm = fmaxf(cm, __shfl_xor(cm, 1));
            cm = fmaxf(cm, __shfl_xor(cm, 2));
            cm = fmaxf(cm, __shfl_xor(cm, 4));
            cm = fmaxf(cm, __shfl_xor(cm, 8));
            const float nm = fmaxf(mi[r], cm);
            const float al = __expf(mi[r] - nm);
            mi[r] = nm;
            float ssum = 0.f;
            #pragma unroll
            for (int mt = 0; mt < 4; ++mt) {
                const float e = __expf(s[mt][r] - nm);
                s[mt][r] = e; ssum += e;
            }
            ssum += __shfl_xor(ssum, 1);
            ssum += __shfl_xor(ssum, 2);
            ssum += __shfl_xor(ssum, 4);
            ssum += __shfl_xor(ssum, 8);
            li[r] = li[r] * al + ssum;
            #pragma unroll
            for (int t = 0; t < 8; ++t) acc[t][r] *= al;
        }

        // ---- P (C-layout) -> per-wave LDS [row][m] bf16 -> A-fragments -----
        #pragma unroll
        for (int mt = 0; mt < 4; ++mt)
            #pragma unroll
            for (int r = 0; r < 4; ++r)
                pl[(quad * 4 + r) * 72 + mt * 16 + ll] =
                    (short)f2b(s[mt][r]);
        bf16x8 pa[2];
        #pragma unroll
        for (int ks = 0; ks < 2; ++ks)
            pa[ks] = *(const bf16x8*)(pl + ll * 72 + ks * 32 + quad * 8);

        // ---- PV: 8 channel-tiles x 2 k-steps -------------------------------
        #pragma unroll
        for (int ct = 0; ct < 8; ++ct) {
            #pragma unroll
            for (int ks = 0; ks < 2; ++ks) {
                const bf16x8 gb = *(const bf16x8*)(
                    gT + (size_t)(ct * 16 + ll) * NPIX_ + m0 + ks * 32 + quad * 8);
                acc[ct] = mfma16(pa[ks], gb, acc[ct]);
            }
        }
    }

    // ---- split-KV merge across the 4 waves (bf16 partials) -----------------
    #pragma unroll
    for (int ct = 0; ct < 8; ++ct)
        #pragma unroll
        for (int r = 0; r < 4; ++r)
            o_lds[w][quad * 4 + r][ct * 16 + ll] = f2b(acc[ct][r]);
    if (ll == 0) {
        #pragma unroll
        for (int r = 0; r < 4; ++r) {
            ml_lds[w][quad * 4 + r][0] = mi[r];
            ml_lds[w][quad * 4 + r][1] = li[r];
        }
    }
    __syncthreads();

    const int n  = tid >> 4;           // 0..15
    const int c0 = (tid & 15) * 8;
    const float M = fmaxf(fmaxf(ml_lds[0][n][0], ml_lds[1][n][0]),
                          fmaxf(ml_lds[2][n][0], ml_lds[3][n][0]));
    float sc[4], L = 0.f;
    #pragma unroll
    for (int ww = 0; ww < 4; ++ww) {
        sc[ww] = __expf(ml_lds[ww][n][0] - M);
        L += ml_lds[ww][n][1] * sc[ww];
    }
    const float inv = 1.f / L;
    unsigned short tmp[8];
    #pragma unroll
    for (int j = 0; j < 8; ++j) {
        float o = 0.f;
        #pragma unroll
        for (int ww = 0; ww < 4; ++ww)
            o += b2f(o_lds[ww][n][c0 + j]) * sc[ww];
        tmp[j] = f2b(o * inv);
    }
    #pragma unroll
    for (int j = 0; j < 8; j += 4)
        *(ushort4*)(g_aob + (size_t)(R0 + n) * 128 + c0 + j) =
            make_ushort4(tmp[j], tmp[j+1], tmp[j+2], tmp[j+3]);
}

// ---------------------------------------------------------------------------
// conv_out_mfma: implicit-GEMM 3x3 conv (128->256, bf16) + fp32 residual
// ---------------------------------------------------------------------------
__global__ __launch_bounds__(256) void conv_out_mfma(
    const float* __restrict__ x, float* __restrict__ out)
{
    const int tid = threadIdx.x;
    const int w = tid >> 6, lane = tid & 63, quad = lane >> 4, ll = lane & 15;
    const int P0 = blockIdx.x * 32;
    const int fb = w * 64;

    int pb[2], ph[2], pw[2];
    #pragma unroll
    for (int pt = 0; pt < 2; ++pt) {
        const int p = P0 + pt * 16 + ll;
        pb[pt] = p / NPIX_;
        const int pl_ = p % NPIX_;
        ph[pt] = pl_ / WW_;
        pw[pt] = pl_ % WW_;
    }

    const bf16x8 ZV = {0,0,0,0,0,0,0,0};
    f32x4 acc[2][4];
    #pragma unroll
    for (int pt = 0; pt < 2; ++pt)
        #pragma unroll
        for (int ft = 0; ft < 4; ++ft) acc[pt][ft] = (f32x4){0.f,0.f,0.f,0.f};

    for (int t = 0; t < 9; ++t) {
        const int dh = t / 3 - 1, dw = t % 3 - 1;
        size_t abase[2]; bool av[2];
        #pragma unroll
        for (int pt = 0; pt < 2; ++pt) {
            const int hh = ph[pt] + dh, ww2 = pw[pt] + dw;
            av[pt] = (hh >= 0 && hh < HH_ && ww2 >= 0 && ww2 < WW_);
            abase[pt] = ((size_t)pb[pt] * NPIX_ + hh * WW_ + ww2) * NF_;
        }
        for (int kc = 0; kc < 4; ++kc) {
            const int ko = kc * 32 + quad * 8;
            bf16x8 a[2];
            #pragma unroll
            for (int pt = 0; pt < 2; ++pt)
                a[pt] = av[pt] ? *(const bf16x8*)(g_aob + abase[pt] + ko) : ZV;
            const int wk = t * 128 + ko;
            #pragma unroll
            for (int ft = 0; ft < 4; ++ft) {
                const bf16x8 bw = *(const bf16x8*)(
                    g_wcT + (size_t)(fb + ft * 16 + ll) * KWC_ + wk);
                #pragma unroll
                for (int pt = 0; pt < 2; ++pt)
                    acc[pt][ft] = mfma16(a[pt], bw, acc[pt][ft]);
            }
        }
    }

    #pragma unroll
    for (int pt = 0; pt < 2; ++pt)
        #pragma unroll
        for (int ft = 0; ft < 4; ++ft) {
            const int f = fb + ft * 16 + ll;
            #pragma unroll
            for (int r = 0; r < 4; ++r) {
                const size_t n = P0 + pt * 16 + quad * 4 + r;
                const size_t oi = n * CIN_ + f;
                out[oi] = x[oi] + acc[pt][ft][r];
            }
        }
}

// ---------------------------------------------------------------------------
extern "C" void kernel_launch(void* const* d_in, const int* in_sizes, int n_in,
                              void* d_out, int out_size, void* d_ws, size_t ws_size,
                              hipStream_t stream)
{
    const float* x  = (const float*)d_in[0];
    const float* wt = (const float*)d_in[1];
    const float* wp = (const float*)d_in[2];
    const float* wg = (const float*)d_in[3];
    const float* wc = (const float*)d_in[4];
    float* out = (float*)d_out;

    prep_x<<<NXEL_ / 4 / 256, 256, 0, stream>>>(x);
    prep_w<<<(WEL_ + 255) / 256, 256, 0, stream>>>(wt, wp, wg, wc);
    conv3_mfma<<<400, 256, 0, stream>>>();
    prep_pack<<<(NELEM_ + 255) / 256, 256, 0, stream>>>();
    attn_mfma<<<NTOK_ / 16, 256, 0, stream>>>();
    conv_out_mfma<<<400, 256, 0, stream>>>(x, out);
}

// Round 3
// 621.492 us; speedup vs baseline: 1.8499x; 1.6358x over previous
//
#include <hip/hip_runtime.h>
#include <hip/hip_bf16.h>

#define HH_ 80
#define WW_ 80
#define CIN_ 256
#define NF_ 128
#define NPIX_ 6400
#define NTOK_ 12800
#define NELEM_ (NTOK_ * NF_)       // 1,638,400
#define NXEL_  (NTOK_ * CIN_)      // 3,276,800
#define KW_    2304                // 9*256  (conv3 K)
#define KWC_   1152                // 9*128  (conv_out K)
#define WEL_   294912

// attention tiling
#define KVS_    4                  // KV splits across blocks
#define KVB_    32                 // m per staged tile
#define MCHUNK_ 1600               // NPIX_/KVS_
#define NIT_    50                 // MCHUNK_/KVB_

// fp32 conv outputs (consumed by prep_pack)
__device__ float g_theta[NELEM_];
__device__ float g_phi  [NELEM_];
__device__ float g_gv   [NELEM_];
// bf16 attention output (consumed by conv_out_mfma)
__device__ unsigned short g_aob[NELEM_];
// bf16 MFMA operands for attention
__device__ unsigned short g_th_hi[NELEM_], g_th_lo[NELEM_];
__device__ unsigned short g_phT_hi[NELEM_], g_phT_lo[NELEM_];
__device__ unsigned short g_gT[NELEM_];
// split-KV fp32 partials (unnormalized O, running m/l)
__device__ float g_po [KVS_ * NELEM_];          // 26 MB
__device__ float g_pml[KVS_ * NTOK_ * 2];
// bf16 hi/lo split of x, and transposed bf16 weights [f][k]
__device__ unsigned short g_xh[NXEL_], g_xl[NXEL_];
__device__ unsigned short g_wtTh[WEL_], g_wtTl[WEL_];
__device__ unsigned short g_wpTh[WEL_], g_wpTl[WEL_];
__device__ unsigned short g_wgT[WEL_];
__device__ unsigned short g_wcT[WEL_];

__device__ __forceinline__ float b2f(unsigned short u) {
    union { unsigned int i; float f; } v; v.i = ((unsigned int)u) << 16; return v.f;
}
__device__ __forceinline__ unsigned short f2b(float f) {
    union { float f; unsigned int i; } v; v.f = f;
    unsigned int i = v.i;
    i += 0x7fffu + ((i >> 16) & 1u);   // RNE (finite only)
    return (unsigned short)(i >> 16);
}

typedef __attribute__((ext_vector_type(8))) short bf16x8;
typedef __attribute__((ext_vector_type(4))) float f32x4;

__device__ __forceinline__ f32x4 mfma16(bf16x8 a, bf16x8 b, f32x4 c) {
    return __builtin_amdgcn_mfma_f32_16x16x32_bf16(a, b, c, 0, 0, 0);
}

// ---------------------------------------------------------------------------
// prep_x: fp32 x -> bf16 hi/lo split
// ---------------------------------------------------------------------------
__global__ __launch_bounds__(256) void prep_x(const float* __restrict__ x)
{
    const int i = (blockIdx.x * 256 + threadIdx.x) * 4;
    if (i >= NXEL_) return;
    const float4 v = *(const float4*)(x + i);
    ushort4 hi, lo;
    hi.x = f2b(v.x); lo.x = f2b(v.x - b2f(hi.x));
    hi.y = f2b(v.y); lo.y = f2b(v.y - b2f(hi.y));
    hi.z = f2b(v.z); lo.z = f2b(v.z - b2f(hi.z));
    hi.w = f2b(v.w); lo.w = f2b(v.w - b2f(hi.w));
    *(ushort4*)(g_xh + i) = hi;
    *(ushort4*)(g_xl + i) = lo;
}

// ---------------------------------------------------------------------------
// prep_w: transpose HWIO weights to [f][k] bf16 (hi/lo for w_theta/w_phi)
// ---------------------------------------------------------------------------
__global__ __launch_bounds__(256) void prep_w(
    const float* __restrict__ wt, const float* __restrict__ wp,
    const float* __restrict__ wg, const float* __restrict__ wc)
{
    const int i = blockIdx.x * 256 + threadIdx.x;
    if (i >= WEL_) return;
    {
        const int t  = i / (256 * 128);
        const int r  = i % (256 * 128);
        const int ci = r >> 7;
        const int f  = r & 127;
        const size_t d = (size_t)f * KW_ + t * 256 + ci;
        const float tv = wt[i];
        const unsigned short th = f2b(tv);
        g_wtTh[d] = th; g_wtTl[d] = f2b(tv - b2f(th));
        const float pv = wp[i];
        const unsigned short ph = f2b(pv);
        g_wpTh[d] = ph; g_wpTl[d] = f2b(pv - b2f(ph));
        g_wgT[d] = f2b(wg[i]);
    }
    {
        const int t  = i / (128 * 256);
        const int r  = i % (128 * 256);
        const int ci = r >> 8;
        const int f  = r & 255;
        g_wcT[(size_t)f * KWC_ + t * 128 + ci] = f2b(wc[i]);
    }
}

// ---------------------------------------------------------------------------
// conv3_mfma: implicit-GEMM 3x3 conv, 3 heads fused (r15, verified).
// ---------------------------------------------------------------------------
__global__ __launch_bounds__(256) void conv3_mfma()
{
    const int tid = threadIdx.x;
    const int w = tid >> 6, lane = tid & 63, quad = lane >> 4, ll = lane & 15;
    const int P0 = blockIdx.x * 32;
    const int fb = w * 32;

    int pb[2], ph[2], pw[2];
    #pragma unroll
    for (int pt = 0; pt < 2; ++pt) {
        const int p = P0 + pt * 16 + ll;
        pb[pt] = p / NPIX_;
        const int pl_ = p % NPIX_;
        ph[pt] = pl_ / WW_;
        pw[pt] = pl_ % WW_;
    }

    const bf16x8 ZV = {0,0,0,0,0,0,0,0};
    f32x4 aT[2][2], aP[2][2], aG[2][2];
    #pragma unroll
    for (int pt = 0; pt < 2; ++pt)
        #pragma unroll
        for (int ft = 0; ft < 2; ++ft) {
            aT[pt][ft] = (f32x4){0.f,0.f,0.f,0.f};
            aP[pt][ft] = (f32x4){0.f,0.f,0.f,0.f};
            aG[pt][ft] = (f32x4){0.f,0.f,0.f,0.f};
        }

    for (int t = 0; t < 9; ++t) {
        const int dh = t / 3 - 1, dw = t % 3 - 1;
        size_t abase[2]; bool av[2];
        #pragma unroll
        for (int pt = 0; pt < 2; ++pt) {
            const int hh = ph[pt] + dh, ww2 = pw[pt] + dw;
            av[pt] = (hh >= 0 && hh < HH_ && ww2 >= 0 && ww2 < WW_);
            abase[pt] = ((size_t)pb[pt] * NPIX_ + hh * WW_ + ww2) * CIN_;
        }
        const int wkb = t * 256;
        for (int kc = 0; kc < 8; ++kc) {
            const int ko = kc * 32 + quad * 8;
            bf16x8 aH[2], aL[2];
            #pragma unroll
            for (int pt = 0; pt < 2; ++pt) {
                if (av[pt]) {
                    aH[pt] = *(const bf16x8*)(g_xh + abase[pt] + ko);
                    aL[pt] = *(const bf16x8*)(g_xl + abase[pt] + ko);
                } else { aH[pt] = ZV; aL[pt] = ZV; }
            }
            const int wk = wkb + ko;
            #pragma unroll
            for (int ft = 0; ft < 2; ++ft) {
                const size_t wo = (size_t)(fb + ft * 16 + ll) * KW_ + wk;
                const bf16x8 tH = *(const bf16x8*)(g_wtTh + wo);
                const bf16x8 tL = *(const bf16x8*)(g_wtTl + wo);
                const bf16x8 pH = *(const bf16x8*)(g_wpTh + wo);
                const bf16x8 pL = *(const bf16x8*)(g_wpTl + wo);
                const bf16x8 gB = *(const bf16x8*)(g_wgT + wo);
                #pragma unroll
                for (int pt = 0; pt < 2; ++pt) {
                    aT[pt][ft] = mfma16(aH[pt], tH, aT[pt][ft]);
                    aT[pt][ft] = mfma16(aH[pt], tL, aT[pt][ft]);
                    aT[pt][ft] = mfma16(aL[pt], tH, aT[pt][ft]);
                    aP[pt][ft] = mfma16(aH[pt], pH, aP[pt][ft]);
                    aP[pt][ft] = mfma16(aH[pt], pL, aP[pt][ft]);
                    aP[pt][ft] = mfma16(aL[pt], pH, aP[pt][ft]);
                    aG[pt][ft] = mfma16(aH[pt], gB, aG[pt][ft]);
                }
            }
        }
    }

    #pragma unroll
    for (int pt = 0; pt < 2; ++pt)
        #pragma unroll
        for (int ft = 0; ft < 2; ++ft) {
            const int f = fb + ft * 16 + ll;
            #pragma unroll
            for (int r = 0; r < 4; ++r) {
                const size_t n = P0 + pt * 16 + quad * 4 + r;
                g_theta[n * NF_ + f] = aT[pt][ft][r];
                g_phi  [n * NF_ + f] = aP[pt][ft][r];
                g_gv   [n * NF_ + f] = aG[pt][ft][r];
            }
        }
}

// ---------------------------------------------------------------------------
// prep_pack (r14, verified)
// ---------------------------------------------------------------------------
__global__ __launch_bounds__(256) void prep_pack()
{
    const int i = blockIdx.x * 256 + threadIdx.x;
    if (i >= NELEM_) return;
    const int n  = i >> 7;
    const int c  = i & 127;
    const int b  = n / NPIX_;
    const int nl = n % NPIX_;

    const float tv = g_theta[i];
    const unsigned short th = f2b(tv);
    g_th_hi[i] = th;
    g_th_lo[i] = f2b(tv - b2f(th));

    const float pv = g_phi[i];
    const int j  = nl * 128 + c;
    const int cp = j / NPIX_;
    const int mp = j % NPIX_;
    const unsigned short phh = f2b(pv);
    const size_t o = (size_t)b * (NPIX_ * NF_) + (size_t)mp * 128 + cp;
    g_phT_hi[o] = phh;
    g_phT_lo[o] = f2b(pv - b2f(phh));

    g_gT[(size_t)b * (NPIX_ * NF_) + (size_t)c * NPIX_ + nl] = f2b(g_gv[i]);
}

// ---------------------------------------------------------------------------
// attn_mfma v5: flash-style, LDS-staged KV, Q-split waves, KV-split blocks.
//
// Diagnosis from v2/v4: both ran at ~6.2 TB/s effective global-load rate
// (latency*concurrency wall: ~1 load in flight/wave x ~500cy), so time
// scaled with streamed bytes. Fixes here:
//  - 64 Q-rows/block, 4 waves x 16 rows (Q-split: no in-block KV merge).
//    Each staged KV byte feeds 4 waves -> total stream 1.92 GB -> 0.96 GB.
//  - Single-LDS-buffer + register prefetch (T14): next tile's 6 global
//    loads issue BEFORE compute, ds_write after the barrier -> load
//    latency hides under 32 MFMAs + softmax.
//  - KV split 4-way across blocks (fp32 partials merged by merge_attn):
//    grid 800, LDS exactly 32 KB -> 4 blocks/CU capacity.
//  - blockIdx&7 -> (batch,kvs) group == XCD: each XCD re-reads one 1.23 MB
//    KV chunk that fits its private 4 MB L2.
// K tiles padded to 136 (stride 272B = 4 banks mod 32 -> 2-way read),
// V tile padded to 40 (stride 80B = 20 banks -> 2-way read).
// ---------------------------------------------------------------------------
__global__ __launch_bounds__(256) void attn_mfma()
{
    __shared__ __align__(16) unsigned short kh_lds[KVB_][136];  // 8.7 KB
    __shared__ __align__(16) unsigned short kl_lds[KVB_][136];  // 8.7 KB
    __shared__ __align__(16) unsigned short v_lds[NF_][40];     // 10 KB
    __shared__ __align__(16) short p_lds[4][16 * 40];           // 5.1 KB

    const int tid  = threadIdx.x;
    const int w    = tid >> 6;
    const int lane = tid & 63;
    const int quad = lane >> 4;
    const int ll   = lane & 15;

    // group g = batch*4 + kvs in [0,8): consecutive blockIdx round-robin
    // across XCDs, so each XCD handles one (batch,kvs) KV chunk.
    const int g   = blockIdx.x & 7;
    const int qw  = blockIdx.x >> 3;        // 0..99
    const int b   = g >> 2;
    const int kvs = g & 3;
    const int R0  = b * NPIX_ + qw * 64;    // 64 Q rows per block
    const int m_start = kvs * MCHUNK_;      // within-batch m offset

    const unsigned short* phH = g_phT_hi + (size_t)b * (NPIX_ * NF_);
    const unsigned short* phL = g_phT_lo + (size_t)b * (NPIX_ * NF_);
    const unsigned short* gT  = g_gT    + (size_t)b * (NPIX_ * NF_);

    // theta A-fragments for this wave's 16 rows
    bf16x8 aH[4], aL[4];
    #pragma unroll
    for (int kk = 0; kk < 4; ++kk) {
        const size_t off = (size_t)(R0 + w * 16 + ll) * 128 + kk * 32 + quad * 8;
        aH[kk] = *(const bf16x8*)(g_th_hi + off);
        aL[kk] = *(const bf16x8*)(g_th_lo + off);
    }

    f32x4 acc[8];
    #pragma unroll
    for (int t = 0; t < 8; ++t) acc[t] = (f32x4){0.f, 0.f, 0.f, 0.f};
    float mi[4], li[4];
    #pragma unroll
    for (int r = 0; r < 4; ++r) { mi[r] = -1e30f; li[r] = 0.f; }

    // staging thread map (row-major: coalesced 16B global reads)
    const int kr0 = tid >> 4;            // K rows 0..15 (and +16)
    const int kc0 = (tid & 15) * 8;      // K col elems
    const int vr0 = tid >> 2;            // V rows 0..63 (and +64)
    const int vm0 = (tid & 3) * 8;       // V m elems

    bf16x8 skh0, skh1, skl0, skl1, sv0, sv1;

    // prologue: stage tile 0
    {
        const int m0 = m_start;
        skh0 = *(const bf16x8*)(phH + (size_t)(m0 + kr0) * 128 + kc0);
        skh1 = *(const bf16x8*)(phH + (size_t)(m0 + kr0 + 16) * 128 + kc0);
        skl0 = *(const bf16x8*)(phL + (size_t)(m0 + kr0) * 128 + kc0);
        skl1 = *(const bf16x8*)(phL + (size_t)(m0 + kr0 + 16) * 128 + kc0);
        sv0  = *(const bf16x8*)(gT + (size_t)vr0 * NPIX_ + m0 + vm0);
        sv1  = *(const bf16x8*)(gT + (size_t)(vr0 + 64) * NPIX_ + m0 + vm0);
        *(bf16x8*)(&kh_lds[kr0][kc0])      = skh0;
        *(bf16x8*)(&kh_lds[kr0 + 16][kc0]) = skh1;
        *(bf16x8*)(&kl_lds[kr0][kc0])      = skl0;
        *(bf16x8*)(&kl_lds[kr0 + 16][kc0]) = skl1;
        *(bf16x8*)(&v_lds[vr0][vm0])       = sv0;
        *(bf16x8*)(&v_lds[vr0 + 64][vm0])  = sv1;
    }
    __syncthreads();

    short* pl = &p_lds[w][0];

    for (int it = 0; it < NIT_; ++it) {
        const bool pf = (it + 1 < NIT_);
        if (pf) {  // issue next tile's loads; consumed after the barrier
            const int m0 = m_start + (it + 1) * KVB_;
            skh0 = *(const bf16x8*)(phH + (size_t)(m0 + kr0) * 128 + kc0);
            skh1 = *(const bf16x8*)(phH + (size_t)(m0 + kr0 + 16) * 128 + kc0);
            skl0 = *(const bf16x8*)(phL + (size_t)(m0 + kr0) * 128 + kc0);
            skl1 = *(const bf16x8*)(phL + (size_t)(m0 + kr0 + 16) * 128 + kc0);
            sv0  = *(const bf16x8*)(gT + (size_t)vr0 * NPIX_ + m0 + vm0);
            sv1  = *(const bf16x8*)(gT + (size_t)(vr0 + 64) * NPIX_ + m0 + vm0);
        }

        // ---- S phase from LDS: 2 m-subtiles x 4 k-steps, hi/lo ------------
        f32x4 s[2];
        #pragma unroll
        for (int mt = 0; mt < 2; ++mt) {
            f32x4 s0 = (f32x4){0.f,0.f,0.f,0.f};
            const int mrow = mt * 16 + ll;
            #pragma unroll
            for (int kk = 0; kk < 4; ++kk) {
                const bf16x8 bH = *(const bf16x8*)(&kh_lds[mrow][kk * 32 + quad * 8]);
                const bf16x8 bL = *(const bf16x8*)(&kl_lds[mrow][kk * 32 + quad * 8]);
                s0 = mfma16(aH[kk], bH, s0);
                s0 = mfma16(aH[kk], bL, s0);
                s0 = mfma16(aL[kk], bH, s0);
            }
            s[mt] = s0;
        }

        // ---- online softmax per row ---------------------------------------
        #pragma unroll
        for (int r = 0; r < 4; ++r) {
            float cm = fmaxf(s[0][r], s[1][r]);
            cm = fmaxf(cm, __shfl_xor(cm, 1));
            cm = fmaxf(cm, __shfl_xor(cm, 2));
            cm = fmaxf(cm, __shfl_xor(cm, 4));
            cm = fmaxf(cm, __shfl_xor(cm, 8));
            const float nm = fmaxf(mi[r], cm);
            const float al = __expf(mi[r] - nm);
            mi[r] = nm;
            float ssum = 0.f;
            #pragma unroll
            for (int mt = 0; mt < 2; ++mt) {
                const float e = __expf(s[mt][r] - nm);
                s[mt][r] = e; ssum += e;
            }
            ssum += __shfl_xor(ssum, 1);
            ssum += __shfl_xor(ssum, 2);
            ssum += __shfl_xor(ssum, 4);
            ssum += __shfl_xor(ssum, 8);
            li[r] = li[r] * al + ssum;
            #pragma unroll
            for (int t = 0; t < 8; ++t) acc[t][r] *= al;
        }

        // ---- P (C-layout) -> per-wave LDS [16 rows][40] -> A-fragment -----
        #pragma unroll
        for (int mt = 0; mt < 2; ++mt)
            #pragma unroll
            for (int r = 0; r < 4; ++r)
                pl[(quad * 4 + r) * 40 + mt * 16 + ll] = (short)f2b(s[mt][r]);
        const bf16x8 pa = *(const bf16x8*)(pl + ll * 40 + quad * 8);

        // ---- PV: 8 channel-tiles, k=32 ------------------------------------
        #pragma unroll
        for (int ct = 0; ct < 8; ++ct) {
            const bf16x8 gb = *(const bf16x8*)(&v_lds[ct * 16 + ll][quad * 8]);
            acc[ct] = mfma16(pa, gb, acc[ct]);
        }

        __syncthreads();               // everyone done reading this tile
        if (pf) {                      // vmcnt wait folds in here, post-compute
            *(bf16x8*)(&kh_lds[kr0][kc0])      = skh0;
            *(bf16x8*)(&kh_lds[kr0 + 16][kc0]) = skh1;
            *(bf16x8*)(&kl_lds[kr0][kc0])      = skl0;
            *(bf16x8*)(&kl_lds[kr0 + 16][kc0]) = skl1;
            *(bf16x8*)(&v_lds[vr0][vm0])       = sv0;
            *(bf16x8*)(&v_lds[vr0 + 64][vm0])  = sv1;
        }
        __syncthreads();               // next tile visible
    }

    // ---- write unnormalized fp32 partials + m/l ----------------------------
    const int row0 = R0 + w * 16;
    #pragma unroll
    for (int ct = 0; ct < 8; ++ct)
        #pragma unroll
        for (int r = 0; r < 4; ++r)
            g_po[((size_t)kvs * NTOK_ + row0 + quad * 4 + r) * NF_ + ct * 16 + ll]
                = acc[ct][r];
    if (ll == 0) {
        #pragma unroll
        for (int r = 0; r < 4; ++r) {
            const size_t mlidx = ((size_t)kvs * NTOK_ + row0 + quad * 4 + r) * 2;
            g_pml[mlidx]     = mi[r];
            g_pml[mlidx + 1] = li[r];
        }
    }
}

// ---------------------------------------------------------------------------
// merge_attn: combine KVS_ fp32 partials -> normalized bf16 g_aob
// ---------------------------------------------------------------------------
__global__ __launch_bounds__(256) void merge_attn()
{
    const int idx = blockIdx.x * 256 + threadIdx.x;   // NTOK_*16 threads
    const int row = idx >> 4;
    const int c0  = (idx & 15) * 8;

    float m[KVS_], l[KVS_];
    #pragma unroll
    for (int s = 0; s < KVS_; ++s) {
        const size_t mlidx = ((size_t)s * NTOK_ + row) * 2;
        m[s] = g_pml[mlidx];
        l[s] = g_pml[mlidx + 1];
    }
    const float M = fmaxf(fmaxf(m[0], m[1]), fmaxf(m[2], m[3]));
    float a[KVS_], L = 0.f;
    #pragma unroll
    for (int s = 0; s < KVS_; ++s) {
        a[s] = __expf(m[s] - M);
        L += a[s] * l[s];
    }
    const float inv = 1.f / L;

    float o[8];
    #pragma unroll
    for (int j = 0; j < 8; ++j) o[j] = 0.f;
    #pragma unroll
    for (int s = 0; s < KVS_; ++s) {
        const float* p = g_po + ((size_t)s * NTOK_ + row) * NF_ + c0;
        const float4 p0 = *(const float4*)(p);
        const float4 p1 = *(const float4*)(p + 4);
        o[0] += a[s] * p0.x; o[1] += a[s] * p0.y;
        o[2] += a[s] * p0.z; o[3] += a[s] * p0.w;
        o[4] += a[s] * p1.x; o[5] += a[s] * p1.y;
        o[6] += a[s] * p1.z; o[7] += a[s] * p1.w;
    }
    unsigned short tmp[8];
    #pragma unroll
    for (int j = 0; j < 8; ++j) tmp[j] = f2b(o[j] * inv);
    unsigned short* dst = g_aob + (size_t)row * NF_ + c0;
    *(ushort4*)(dst)     = make_ushort4(tmp[0], tmp[1], tmp[2], tmp[3]);
    *(ushort4*)(dst + 4) = make_ushort4(tmp[4], tmp[5], tmp[6], tmp[7]);
}

// ---------------------------------------------------------------------------
// conv_out_mfma: implicit-GEMM 3x3 conv (128->256, bf16) + fp32 residual
// ---------------------------------------------------------------------------
__global__ __launch_bounds__(256) void conv_out_mfma(
    const float* __restrict__ x, float* __restrict__ out)
{
    const int tid = threadIdx.x;
    const int w = tid >> 6, lane = tid & 63, quad = lane >> 4, ll = lane & 15;
    const int P0 = blockIdx.x * 32;
    const int fb = w * 64;

    int pb[2], ph[2], pw[2];
    #pragma unroll
    for (int pt = 0; pt < 2; ++pt) {
        const int p = P0 + pt * 16 + ll;
        pb[pt] = p / NPIX_;
        const int pl_ = p % NPIX_;
        ph[pt] = pl_ / WW_;
        pw[pt] = pl_ % WW_;
    }

    const bf16x8 ZV = {0,0,0,0,0,0,0,0};
    f32x4 acc[2][4];
    #pragma unroll
    for (int pt = 0; pt < 2; ++pt)
        #pragma unroll
        for (int ft = 0; ft < 4; ++ft) acc[pt][ft] = (f32x4){0.f,0.f,0.f,0.f};

    for (int t = 0; t < 9; ++t) {
        const int dh = t / 3 - 1, dw = t % 3 - 1;
        size_t abase[2]; bool av[2];
        #pragma unroll
        for (int pt = 0; pt < 2; ++pt) {
            const int hh = ph[pt] + dh, ww2 = pw[pt] + dw;
            av[pt] = (hh >= 0 && hh < HH_ && ww2 >= 0 && ww2 < WW_);
            abase[pt] = ((size_t)pb[pt] * NPIX_ + hh * WW_ + ww2) * NF_;
        }
        for (int kc = 0; kc < 4; ++kc) {
            const int ko = kc * 32 + quad * 8;
            bf16x8 a[2];
            #pragma unroll
            for (int pt = 0; pt < 2; ++pt)
                a[pt] = av[pt] ? *(const bf16x8*)(g_aob + abase[pt] + ko) : ZV;
            const int wk = t * 128 + ko;
            #pragma unroll
            for (int ft = 0; ft < 4; ++ft) {
                const bf16x8 bw = *(const bf16x8*)(
                    g_wcT + (size_t)(fb + ft * 16 + ll) * KWC_ + wk);
                #pragma unroll
                for (int pt = 0; pt < 2; ++pt)
                    acc[pt][ft] = mfma16(a[pt], bw, acc[pt][ft]);
            }
        }
    }

    #pragma unroll
    for (int pt = 0; pt < 2; ++pt)
        #pragma unroll
        for (int ft = 0; ft < 4; ++ft) {
            const int f = fb + ft * 16 + ll;
            #pragma unroll
            for (int r = 0; r < 4; ++r) {
                const size_t n = P0 + pt * 16 + quad * 4 + r;
                const size_t oi = n * CIN_ + f;
                out[oi] = x[oi] + acc[pt][ft][r];
            }
        }
}

// ---------------------------------------------------------------------------
extern "C" void kernel_launch(void* const* d_in, const int* in_sizes, int n_in,
                              void* d_out, int out_size, void* d_ws, size_t ws_size,
                              hipStream_t stream)
{
    const float* x  = (const float*)d_in[0];
    const float* wt = (const float*)d_in[1];
    const float* wp = (const float*)d_in[2];
    const float* wg = (const float*)d_in[3];
    const float* wc = (const float*)d_in[4];
    float* out = (float*)d_out;

    prep_x<<<NXEL_ / 4 / 256, 256, 0, stream>>>(x);
    prep_w<<<(WEL_ + 255) / 256, 256, 0, stream>>>(wt, wp, wg, wc);
    conv3_mfma<<<400, 256, 0, stream>>>();
    prep_pack<<<(NELEM_ + 255) / 256, 256, 0, stream>>>();
    attn_mfma<<<(NTOK_ / 64) * KVS_, 256, 0, stream>>>();
    merge_attn<<<NTOK_ * 16 / 256, 256, 0, stream>>>();
    conv_out_mfma<<<400, 256, 0, stream>>>(x, out);
}

// Round 4
// 476.707 us; speedup vs baseline: 2.4117x; 1.3037x over previous
//
#include <hip/hip_runtime.h>
#include <hip/hip_bf16.h>

#define HH_ 80
#define WW_ 80
#define CIN_ 256
#define NF_ 128
#define NPIX_ 6400
#define NTOK_ 12800
#define NELEM_ (NTOK_ * NF_)       // 1,638,400
#define NXEL_  (NTOK_ * CIN_)      // 3,276,800
#define KW_    2304                // 9*256  (conv3 K)
#define KWC_   1152                // 9*128  (conv_out K)
#define WEL_   294912

// attention tiling
#define KVS_    4                  // KV splits across blocks
#define KVB_    32                 // m per staged tile
#define MCHUNK_ 1600               // NPIX_/KVS_
#define NIT_    50                 // MCHUNK_/KVB_

// fp32 conv outputs (consumed by prep_pack)
__device__ float g_theta[NELEM_];
__device__ float g_phi  [NELEM_];
__device__ float g_gv   [NELEM_];
// bf16 attention output (consumed by conv_out_mfma)
__device__ unsigned short g_aob[NELEM_];
// bf16 MFMA operands for attention
__device__ unsigned short g_th_hi[NELEM_], g_th_lo[NELEM_];
__device__ unsigned short g_phT_hi[NELEM_], g_phT_lo[NELEM_];
__device__ unsigned short g_gT[NELEM_];
// split-KV fp32 partials (unnormalized O, running m/l)
__device__ float g_po [KVS_ * NELEM_];          // 26 MB
__device__ float g_pml[KVS_ * NTOK_ * 2];
// bf16 hi/lo split of x, and transposed bf16 weights
// attn-conv weights: chunk-major [72 chunks][128 f][32 ch] (chunk = t*8+kc)
__device__ unsigned short g_xh[NXEL_], g_xl[NXEL_];
__device__ unsigned short g_wtTh[WEL_], g_wtTl[WEL_];
__device__ unsigned short g_wpTh[WEL_], g_wpTl[WEL_];
__device__ unsigned short g_wgT[WEL_];
__device__ unsigned short g_wcT[WEL_];          // conv_out: [f][k] (unchanged)

__device__ __forceinline__ float b2f(unsigned short u) {
    union { unsigned int i; float f; } v; v.i = ((unsigned int)u) << 16; return v.f;
}
__device__ __forceinline__ unsigned short f2b(float f) {
    union { float f; unsigned int i; } v; v.f = f;
    unsigned int i = v.i;
    i += 0x7fffu + ((i >> 16) & 1u);   // RNE (finite only)
    return (unsigned short)(i >> 16);
}

typedef __attribute__((ext_vector_type(8))) short bf16x8;
typedef __attribute__((ext_vector_type(4))) float f32x4;

__device__ __forceinline__ f32x4 mfma16(bf16x8 a, bf16x8 b, f32x4 c) {
    return __builtin_amdgcn_mfma_f32_16x16x32_bf16(a, b, c, 0, 0, 0);
}

// ---------------------------------------------------------------------------
// prep_x: fp32 x -> bf16 hi/lo split
// ---------------------------------------------------------------------------
__global__ __launch_bounds__(256) void prep_x(const float* __restrict__ x)
{
    const int i = (blockIdx.x * 256 + threadIdx.x) * 4;
    if (i >= NXEL_) return;
    const float4 v = *(const float4*)(x + i);
    ushort4 hi, lo;
    hi.x = f2b(v.x); lo.x = f2b(v.x - b2f(hi.x));
    hi.y = f2b(v.y); lo.y = f2b(v.y - b2f(hi.y));
    hi.z = f2b(v.z); lo.z = f2b(v.z - b2f(hi.z));
    hi.w = f2b(v.w); lo.w = f2b(v.w - b2f(hi.w));
    *(ushort4*)(g_xh + i) = hi;
    *(ushort4*)(g_xl + i) = lo;
}

// ---------------------------------------------------------------------------
// prep_w: attn-conv weights -> chunk-major [72][128][32] bf16 (hi/lo for
// w_theta/w_phi); conv_out weights -> [f][k] (unchanged).
// ---------------------------------------------------------------------------
__global__ __launch_bounds__(256) void prep_w(
    const float* __restrict__ wt, const float* __restrict__ wp,
    const float* __restrict__ wg, const float* __restrict__ wc)
{
    const int i = blockIdx.x * 256 + threadIdx.x;
    if (i >= WEL_) return;
    {
        const int t  = i / (256 * 128);
        const int r  = i % (256 * 128);
        const int ci = r >> 7;
        const int f  = r & 127;
        const size_t d = (size_t)(t * 8 + (ci >> 5)) * 4096
                       + (size_t)f * 32 + (ci & 31);
        const float tv = wt[i];
        const unsigned short th = f2b(tv);
        g_wtTh[d] = th; g_wtTl[d] = f2b(tv - b2f(th));
        const float pv = wp[i];
        const unsigned short ph = f2b(pv);
        g_wpTh[d] = ph; g_wpTl[d] = f2b(pv - b2f(ph));
        g_wgT[d] = f2b(wg[i]);
    }
    {
        const int t  = i / (128 * 256);
        const int r  = i % (128 * 256);
        const int ci = r >> 8;
        const int f  = r & 255;
        g_wcT[(size_t)f * KWC_ + t * 128 + ci] = f2b(wc[i]);
    }
}

// ---------------------------------------------------------------------------
// conv3_mfma v2: LDS-staged implicit-GEMM 3x3 conv, 3 heads fused.
//
// v1 (r15) read all operands from global: 1008 x 1KB issued loads/wave =
// 1.65 GB at the ~6.8 TB/s issued-load wall = 243us (MfmaUtil 8.8%,
// LDS unused). v2: block = 64 pix x 128 f, 512 thr (8 waves = 2 pixel-
// groups x 4 filter-groups, wave tile 32x32). Per step (t,kc): stage
// 40KB weights + 8KB x (hi/lo, boundary zeros folded in -> branch-free
// MFMA loop) into LDS, single-buffered with register prefetch one step
// ahead (T14): 6x16B global loads issue before compute, ds_write after
// the barrier. Weights chunk-major [72][128][32] -> staging is a fully
// contiguous 8KB stream per tensor. Global issued 1.65 GB -> 691 MB;
// LDS-pipe floor ~37us, MFMA floor ~25us (hidden under it).
// LDS rows 80B stride -> uniform 8-slot bank schedule for b128.
// ---------------------------------------------------------------------------
__global__ __launch_bounds__(512) void conv3_mfma()
{
    __shared__ __align__(16) unsigned short w_lds[5][128][40];   // 50 KB
    __shared__ __align__(16) unsigned short x_lds[64][2][40];    // 10 KB

    const int tid  = threadIdx.x;
    const int wv   = tid >> 6;
    const int lane = tid & 63;
    const int quad = lane >> 4;
    const int ll   = lane & 15;
    const int wp   = wv >> 2;          // pixel group 0..1
    const int wf   = wv & 3;           // filter group 0..3
    const int P0   = blockIdx.x * 64;
    const int fb   = wf * 32;

    // staging thread maps
    const int sxp = tid >> 3;          // x: pixel 0..63
    const int sxh = (tid >> 2) & 1;    // x: hi/lo
    const int sxc = (tid & 3) * 8;     // x: ch offset
    const int swf = tid >> 2;          // w: filter 0..127
    const int swc = (tid & 3) * 8;     // w: ch offset

    // x staging source pixel coords
    const int sp  = P0 + sxp;
    const int spb = sp / NPIX_;
    const int spl = sp % NPIX_;
    const int sph = spl / WW_;
    const int spw = spl % WW_;

    const bf16x8 ZV = {0,0,0,0,0,0,0,0};
    bf16x8 rx, rw0, rw1, rw2, rw3, rw4;

#define C3_STAGE_LOAD(s)                                                      \
    {                                                                         \
        const int t_ = (s) >> 3, kc_ = (s) & 7;                               \
        const int hh_ = sph + t_ / 3 - 1, ww_ = spw + t_ % 3 - 1;             \
        if (hh_ >= 0 && hh_ < HH_ && ww_ >= 0 && ww_ < WW_) {                 \
            const size_t src_ = ((size_t)spb * NPIX_ + hh_ * WW_ + ww_) * CIN_\
                                + kc_ * 32 + sxc;                             \
            rx = sxh ? *(const bf16x8*)(g_xl + src_)                          \
                     : *(const bf16x8*)(g_xh + src_);                         \
        } else rx = ZV;                                                       \
        const size_t ws_ = (size_t)(s) * 4096 + (size_t)swf * 32 + swc;       \
        rw0 = *(const bf16x8*)(g_wtTh + ws_);                                 \
        rw1 = *(const bf16x8*)(g_wtTl + ws_);                                 \
        rw2 = *(const bf16x8*)(g_wpTh + ws_);                                 \
        rw3 = *(const bf16x8*)(g_wpTl + ws_);                                 \
        rw4 = *(const bf16x8*)(g_wgT  + ws_);                                 \
    }

#define C3_STAGE_WRITE()                                                      \
    {                                                                         \
        *(bf16x8*)(&x_lds[sxp][sxh][sxc]) = rx;                               \
        *(bf16x8*)(&w_lds[0][swf][swc]) = rw0;                                \
        *(bf16x8*)(&w_lds[1][swf][swc]) = rw1;                                \
        *(bf16x8*)(&w_lds[2][swf][swc]) = rw2;                                \
        *(bf16x8*)(&w_lds[3][swf][swc]) = rw3;                                \
        *(bf16x8*)(&w_lds[4][swf][swc]) = rw4;                                \
    }

    f32x4 aT[2][2], aP[2][2], aG[2][2];   // [pt][ft]
    #pragma unroll
    for (int pt = 0; pt < 2; ++pt)
        #pragma unroll
        for (int ft = 0; ft < 2; ++ft) {
            aT[pt][ft] = (f32x4){0.f,0.f,0.f,0.f};
            aP[pt][ft] = (f32x4){0.f,0.f,0.f,0.f};
            aG[pt][ft] = (f32x4){0.f,0.f,0.f,0.f};
        }

    C3_STAGE_LOAD(0);
    C3_STAGE_WRITE();
    __syncthreads();

    for (int s = 0; s < 72; ++s) {
        const bool pf = (s + 1 < 72);
        if (pf) C3_STAGE_LOAD(s + 1);

        bf16x8 xa[2][2];   // [pt][hi/lo]
        #pragma unroll
        for (int pt = 0; pt < 2; ++pt) {
            const int px = wp * 32 + pt * 16 + ll;
            xa[pt][0] = *(const bf16x8*)(&x_lds[px][0][quad * 8]);
            xa[pt][1] = *(const bf16x8*)(&x_lds[px][1][quad * 8]);
        }
        #pragma unroll
        for (int ft = 0; ft < 2; ++ft) {
            const int f = fb + ft * 16 + ll;
            const bf16x8 tH = *(const bf16x8*)(&w_lds[0][f][quad * 8]);
            const bf16x8 tL = *(const bf16x8*)(&w_lds[1][f][quad * 8]);
            const bf16x8 pH = *(const bf16x8*)(&w_lds[2][f][quad * 8]);
            const bf16x8 pL = *(const bf16x8*)(&w_lds[3][f][quad * 8]);
            const bf16x8 gB = *(const bf16x8*)(&w_lds[4][f][quad * 8]);
            #pragma unroll
            for (int pt = 0; pt < 2; ++pt) {
                aT[pt][ft] = mfma16(xa[pt][0], tH, aT[pt][ft]);
                aT[pt][ft] = mfma16(xa[pt][0], tL, aT[pt][ft]);
                aT[pt][ft] = mfma16(xa[pt][1], tH, aT[pt][ft]);
                aP[pt][ft] = mfma16(xa[pt][0], pH, aP[pt][ft]);
                aP[pt][ft] = mfma16(xa[pt][0], pL, aP[pt][ft]);
                aP[pt][ft] = mfma16(xa[pt][1], pH, aP[pt][ft]);
                aG[pt][ft] = mfma16(xa[pt][0], gB, aG[pt][ft]);
            }
        }

        __syncthreads();               // all reads of this tile done
        if (pf) C3_STAGE_WRITE();      // vmcnt wait folds in here
        __syncthreads();               // next tile visible
    }

    #pragma unroll
    for (int pt = 0; pt < 2; ++pt)
        #pragma unroll
        for (int ft = 0; ft < 2; ++ft) {
            const int f = fb + ft * 16 + ll;
            #pragma unroll
            for (int r = 0; r < 4; ++r) {
                const size_t n = P0 + wp * 32 + pt * 16 + quad * 4 + r;
                g_theta[n * NF_ + f] = aT[pt][ft][r];
                g_phi  [n * NF_ + f] = aP[pt][ft][r];
                g_gv   [n * NF_ + f] = aG[pt][ft][r];
            }
        }
#undef C3_STAGE_LOAD
#undef C3_STAGE_WRITE
}

// ---------------------------------------------------------------------------
// prep_pack (r14, verified)
// ---------------------------------------------------------------------------
__global__ __launch_bounds__(256) void prep_pack()
{
    const int i = blockIdx.x * 256 + threadIdx.x;
    if (i >= NELEM_) return;
    const int n  = i >> 7;
    const int c  = i & 127;
    const int b  = n / NPIX_;
    const int nl = n % NPIX_;

    const float tv = g_theta[i];
    const unsigned short th = f2b(tv);
    g_th_hi[i] = th;
    g_th_lo[i] = f2b(tv - b2f(th));

    const float pv = g_phi[i];
    const int j  = nl * 128 + c;
    const int cp = j / NPIX_;
    const int mp = j % NPIX_;
    const unsigned short phh = f2b(pv);
    const size_t o = (size_t)b * (NPIX_ * NF_) + (size_t)mp * 128 + cp;
    g_phT_hi[o] = phh;
    g_phT_lo[o] = f2b(pv - b2f(phh));

    g_gT[(size_t)b * (NPIX_ * NF_) + (size_t)c * NPIX_ + nl] = f2b(g_gv[i]);
}

// ---------------------------------------------------------------------------
// attn_mfma v5: flash-style, LDS-staged KV, Q-split waves, KV-split blocks.
// (verified r3: dropped attn below conv3's 243us)
// ---------------------------------------------------------------------------
__global__ __launch_bounds__(256) void attn_mfma()
{
    __shared__ __align__(16) unsigned short kh_lds[KVB_][136];  // 8.7 KB
    __shared__ __align__(16) unsigned short kl_lds[KVB_][136];  // 8.7 KB
    __shared__ __align__(16) unsigned short v_lds[NF_][40];     // 10 KB
    __shared__ __align__(16) short p_lds[4][16 * 40];           // 5.1 KB

    const int tid  = threadIdx.x;
    const int w    = tid >> 6;
    const int lane = tid & 63;
    const int quad = lane >> 4;
    const int ll   = lane & 15;

    const int g   = blockIdx.x & 7;
    const int qw  = blockIdx.x >> 3;        // 0..99
    const int b   = g >> 2;
    const int kvs = g & 3;
    const int R0  = b * NPIX_ + qw * 64;    // 64 Q rows per block
    const int m_start = kvs * MCHUNK_;      // within-batch m offset

    const unsigned short* phH = g_phT_hi + (size_t)b * (NPIX_ * NF_);
    const unsigned short* phL = g_phT_lo + (size_t)b * (NPIX_ * NF_);
    const unsigned short* gT  = g_gT    + (size_t)b * (NPIX_ * NF_);

    // theta A-fragments for this wave's 16 rows
    bf16x8 aH[4], aL[4];
    #pragma unroll
    for (int kk = 0; kk < 4; ++kk) {
        const size_t off = (size_t)(R0 + w * 16 + ll) * 128 + kk * 32 + quad * 8;
        aH[kk] = *(const bf16x8*)(g_th_hi + off);
        aL[kk] = *(const bf16x8*)(g_th_lo + off);
    }

    f32x4 acc[8];
    #pragma unroll
    for (int t = 0; t < 8; ++t) acc[t] = (f32x4){0.f, 0.f, 0.f, 0.f};
    float mi[4], li[4];
    #pragma unroll
    for (int r = 0; r < 4; ++r) { mi[r] = -1e30f; li[r] = 0.f; }

    const int kr0 = tid >> 4;            // K rows 0..15 (and +16)
    const int kc0 = (tid & 15) * 8;      // K col elems
    const int vr0 = tid >> 2;            // V rows 0..63 (and +64)
    const int vm0 = (tid & 3) * 8;       // V m elems

    bf16x8 skh0, skh1, skl0, skl1, sv0, sv1;

    {
        const int m0 = m_start;
        skh0 = *(const bf16x8*)(phH + (size_t)(m0 + kr0) * 128 + kc0);
        skh1 = *(const bf16x8*)(phH + (size_t)(m0 + kr0 + 16) * 128 + kc0);
        skl0 = *(const bf16x8*)(phL + (size_t)(m0 + kr0) * 128 + kc0);
        skl1 = *(const bf16x8*)(phL + (size_t)(m0 + kr0 + 16) * 128 + kc0);
        sv0  = *(const bf16x8*)(gT + (size_t)vr0 * NPIX_ + m0 + vm0);
        sv1  = *(const bf16x8*)(gT + (size_t)(vr0 + 64) * NPIX_ + m0 + vm0);
        *(bf16x8*)(&kh_lds[kr0][kc0])      = skh0;
        *(bf16x8*)(&kh_lds[kr0 + 16][kc0]) = skh1;
        *(bf16x8*)(&kl_lds[kr0][kc0])      = skl0;
        *(bf16x8*)(&kl_lds[kr0 + 16][kc0]) = skl1;
        *(bf16x8*)(&v_lds[vr0][vm0])       = sv0;
        *(bf16x8*)(&v_lds[vr0 + 64][vm0])  = sv1;
    }
    __syncthreads();

    short* pl = &p_lds[w][0];

    for (int it = 0; it < NIT_; ++it) {
        const bool pf = (it + 1 < NIT_);
        if (pf) {
            const int m0 = m_start + (it + 1) * KVB_;
            skh0 = *(const bf16x8*)(phH + (size_t)(m0 + kr0) * 128 + kc0);
            skh1 = *(const bf16x8*)(phH + (size_t)(m0 + kr0 + 16) * 128 + kc0);
            skl0 = *(const bf16x8*)(phL + (size_t)(m0 + kr0) * 128 + kc0);
            skl1 = *(const bf16x8*)(phL + (size_t)(m0 + kr0 + 16) * 128 + kc0);
            sv0  = *(const bf16x8*)(gT + (size_t)vr0 * NPIX_ + m0 + vm0);
            sv1  = *(const bf16x8*)(gT + (size_t)(vr0 + 64) * NPIX_ + m0 + vm0);
        }

        f32x4 s[2];
        #pragma unroll
        for (int mt = 0; mt < 2; ++mt) {
            f32x4 s0 = (f32x4){0.f,0.f,0.f,0.f};
            const int mrow = mt * 16 + ll;
            #pragma unroll
            for (int kk = 0; kk < 4; ++kk) {
                const bf16x8 bH = *(const bf16x8*)(&kh_lds[mrow][kk * 32 + quad * 8]);
                const bf16x8 bL = *(const bf16x8*)(&kl_lds[mrow][kk * 32 + quad * 8]);
                s0 = mfma16(aH[kk], bH, s0);
                s0 = mfma16(aH[kk], bL, s0);
                s0 = mfma16(aL[kk], bH, s0);
            }
            s[mt] = s0;
        }

        #pragma unroll
        for (int r = 0; r < 4; ++r) {
            float cm = fmaxf(s[0][r], s[1][r]);
            cm = fmaxf(cm, __shfl_xor(cm, 1));
            cm = fmaxf(cm, __shfl_xor(cm, 2));
            cm = fmaxf(cm, __shfl_xor(cm, 4));
            cm = fmaxf(cm, __shfl_xor(cm, 8));
            const float nm = fmaxf(mi[r], cm);
            const float al = __expf(mi[r] - nm);
            mi[r] = nm;
            float ssum = 0.f;
            #pragma unroll
            for (int mt = 0; mt < 2; ++mt) {
                const float e = __expf(s[mt][r] - nm);
                s[mt][r] = e; ssum += e;
            }
            ssum += __shfl_xor(ssum, 1);
            ssum += __shfl_xor(ssum, 2);
            ssum += __shfl_xor(ssum, 4);
            ssum += __shfl_xor(ssum, 8);
            li[r] = li[r] * al + ssum;
            #pragma unroll
            for (int t = 0; t < 8; ++t) acc[t][r] *= al;
        }

        #pragma unroll
        for (int mt = 0; mt < 2; ++mt)
            #pragma unroll
            for (int r = 0; r < 4; ++r)
                pl[(quad * 4 + r) * 40 + mt * 16 + ll] = (short)f2b(s[mt][r]);
        const bf16x8 pa = *(const bf16x8*)(pl + ll * 40 + quad * 8);

        #pragma unroll
        for (int ct = 0; ct < 8; ++ct) {
            const bf16x8 gb = *(const bf16x8*)(&v_lds[ct * 16 + ll][quad * 8]);
            acc[ct] = mfma16(pa, gb, acc[ct]);
        }

        __syncthreads();
        if (pf) {
            *(bf16x8*)(&kh_lds[kr0][kc0])      = skh0;
            *(bf16x8*)(&kh_lds[kr0 + 16][kc0]) = skh1;
            *(bf16x8*)(&kl_lds[kr0][kc0])      = skl0;
            *(bf16x8*)(&kl_lds[kr0 + 16][kc0]) = skl1;
            *(bf16x8*)(&v_lds[vr0][vm0])       = sv0;
            *(bf16x8*)(&v_lds[vr0 + 64][vm0])  = sv1;
        }
        __syncthreads();
    }

    const int row0 = R0 + w * 16;
    #pragma unroll
    for (int ct = 0; ct < 8; ++ct)
        #pragma unroll
        for (int r = 0; r < 4; ++r)
            g_po[((size_t)kvs * NTOK_ + row0 + quad * 4 + r) * NF_ + ct * 16 + ll]
                = acc[ct][r];
    if (ll == 0) {
        #pragma unroll
        for (int r = 0; r < 4; ++r) {
            const size_t mlidx = ((size_t)kvs * NTOK_ + row0 + quad * 4 + r) * 2;
            g_pml[mlidx]     = mi[r];
            g_pml[mlidx + 1] = li[r];
        }
    }
}

// ---------------------------------------------------------------------------
// merge_attn: combine KVS_ fp32 partials -> normalized bf16 g_aob
// ---------------------------------------------------------------------------
__global__ __launch_bounds__(256) void merge_attn()
{
    const int idx = blockIdx.x * 256 + threadIdx.x;   // NTOK_*16 threads
    const int row = idx >> 4;
    const int c0  = (idx & 15) * 8;

    float m[KVS_], l[KVS_];
    #pragma unroll
    for (int s = 0; s < KVS_; ++s) {
        const size_t mlidx = ((size_t)s * NTOK_ + row) * 2;
        m[s] = g_pml[mlidx];
        l[s] = g_pml[mlidx + 1];
    }
    const float M = fmaxf(fmaxf(m[0], m[1]), fmaxf(m[2], m[3]));
    float a[KVS_], L = 0.f;
    #pragma unroll
    for (int s = 0; s < KVS_; ++s) {
        a[s] = __expf(m[s] - M);
        L += a[s] * l[s];
    }
    const float inv = 1.f / L;

    float o[8];
    #pragma unroll
    for (int j = 0; j < 8; ++j) o[j] = 0.f;
    #pragma unroll
    for (int s = 0; s < KVS_; ++s) {
        const float* p = g_po + ((size_t)s * NTOK_ + row) * NF_ + c0;
        const float4 p0 = *(const float4*)(p);
        const float4 p1 = *(const float4*)(p + 4);
        o[0] += a[s] * p0.x; o[1] += a[s] * p0.y;
        o[2] += a[s] * p0.z; o[3] += a[s] * p0.w;
        o[4] += a[s] * p1.x; o[5] += a[s] * p1.y;
        o[6] += a[s] * p1.z; o[7] += a[s] * p1.w;
    }
    unsigned short tmp[8];
    #pragma unroll
    for (int j = 0; j < 8; ++j) tmp[j] = f2b(o[j] * inv);
    unsigned short* dst = g_aob + (size_t)row * NF_ + c0;
    *(ushort4*)(dst)     = make_ushort4(tmp[0], tmp[1], tmp[2], tmp[3]);
    *(ushort4*)(dst + 4) = make_ushort4(tmp[4], tmp[5], tmp[6], tmp[7]);
}

// ---------------------------------------------------------------------------
// conv_out_mfma: implicit-GEMM 3x3 conv (128->256, bf16) + fp32 residual
// ---------------------------------------------------------------------------
__global__ __launch_bounds__(256) void conv_out_mfma(
    const float* __restrict__ x, float* __restrict__ out)
{
    const int tid = threadIdx.x;
    const int w = tid >> 6, lane = tid & 63, quad = lane >> 4, ll = lane & 15;
    const int P0 = blockIdx.x * 32;
    const int fb = w * 64;

    int pb[2], ph[2], pw[2];
    #pragma unroll
    for (int pt = 0; pt < 2; ++pt) {
        const int p = P0 + pt * 16 + ll;
        pb[pt] = p / NPIX_;
        const int pl_ = p % NPIX_;
        ph[pt] = pl_ / WW_;
        pw[pt] = pl_ % WW_;
    }

    const bf16x8 ZV = {0,0,0,0,0,0,0,0};
    f32x4 acc[2][4];
    #pragma unroll
    for (int pt = 0; pt < 2; ++pt)
        #pragma unroll
        for (int ft = 0; ft < 4; ++ft) acc[pt][ft] = (f32x4){0.f,0.f,0.f,0.f};

    for (int t = 0; t < 9; ++t) {
        const int dh = t / 3 - 1, dw = t % 3 - 1;
        size_t abase[2]; bool av[2];
        #pragma unroll
        for (int pt = 0; pt < 2; ++pt) {
            const int hh = ph[pt] + dh, ww2 = pw[pt] + dw;
            av[pt] = (hh >= 0 && hh < HH_ && ww2 >= 0 && ww2 < WW_);
            abase[pt] = ((size_t)pb[pt] * NPIX_ + hh * WW_ + ww2) * NF_;
        }
        for (int kc = 0; kc < 4; ++kc) {
            const int ko = kc * 32 + quad * 8;
            bf16x8 a[2];
            #pragma unroll
            for (int pt = 0; pt < 2; ++pt)
                a[pt] = av[pt] ? *(const bf16x8*)(g_aob + abase[pt] + ko) : ZV;
            const int wk = t * 128 + ko;
            #pragma unroll
            for (int ft = 0; ft < 4; ++ft) {
                const bf16x8 bw = *(const bf16x8*)(
                    g_wcT + (size_t)(fb + ft * 16 + ll) * KWC_ + wk);
                #pragma unroll
                for (int pt = 0; pt < 2; ++pt)
                    acc[pt][ft] = mfma16(a[pt], bw, acc[pt][ft]);
            }
        }
    }

    #pragma unroll
    for (int pt = 0; pt < 2; ++pt)
        #pragma unroll
        for (int ft = 0; ft < 4; ++ft) {
            const int f = fb + ft * 16 + ll;
            #pragma unroll
            for (int r = 0; r < 4; ++r) {
                const size_t n = P0 + pt * 16 + quad * 4 + r;
                const size_t oi = n * CIN_ + f;
                out[oi] = x[oi] + acc[pt][ft][r];
            }
        }
}

// ---------------------------------------------------------------------------
extern "C" void kernel_launch(void* const* d_in, const int* in_sizes, int n_in,
                              void* d_out, int out_size, void* d_ws, size_t ws_size,
                              hipStream_t stream)
{
    const float* x  = (const float*)d_in[0];
    const float* wt = (const float*)d_in[1];
    const float* wp = (const float*)d_in[2];
    const float* wg = (const float*)d_in[3];
    const float* wc = (const float*)d_in[4];
    float* out = (float*)d_out;

    prep_x<<<NXEL_ / 4 / 256, 256, 0, stream>>>(x);
    prep_w<<<(WEL_ + 255) / 256, 256, 0, stream>>>(wt, wp, wg, wc);
    conv3_mfma<<<NTOK_ / 64, 512, 0, stream>>>();
    prep_pack<<<(NELEM_ + 255) / 256, 256, 0, stream>>>();
    attn_mfma<<<(NTOK_ / 64) * KVS_, 256, 0, stream>>>();
    merge_attn<<<NTOK_ * 16 / 256, 256, 0, stream>>>();
    conv_out_mfma<<<400, 256, 0, stream>>>(x, out);
}

// Round 6
// 406.491 us; speedup vs baseline: 2.8283x; 1.1727x over previous
//
#include <hip/hip_runtime.h>
#include <hip/hip_bf16.h>

#define HH_ 80
#define WW_ 80
#define CIN_ 256
#define NF_ 128
#define NPIX_ 6400
#define NTOK_ 12800
#define NELEM_ (NTOK_ * NF_)       // 1,638,400
#define NXEL_  (NTOK_ * CIN_)      // 3,276,800
#define KW_    2304                // 9*256  (conv3 K)
#define KWC_   1152                // 9*128  (conv_out K)
#define WEL_   294912

// attention tiling
#define KVS_    8                  // KV splits across blocks
#define KVB_    32                 // m per staged tile
#define MCHUNK_ 800                // NPIX_/KVS_
#define NIT_    25                 // MCHUNK_/KVB_

// fp32 conv outputs (consumed by prep_pack)
__device__ float g_theta[NELEM_];
__device__ float g_phi  [NELEM_];
__device__ float g_gv   [NELEM_];
// bf16 attention output (consumed by conv_out_mfma)
__device__ unsigned short g_aob[NELEM_];
// bf16 MFMA operands for attention
__device__ unsigned short g_th_hi[NELEM_], g_th_lo[NELEM_];
__device__ unsigned short g_phT_hi[NELEM_], g_phT_lo[NELEM_];
__device__ unsigned short g_gT[NELEM_];
// split-KV fp32 partials (unnormalized O, running m/l)
__device__ float g_po [KVS_ * NELEM_];          // 52 MB
__device__ float g_pml[KVS_ * NTOK_ * 2];
// bf16 hi/lo split of x, and transposed bf16 weights
// attn-conv weights: chunk-major [72 chunks][128 f][32 ch] (chunk = t*8+kc)
__device__ unsigned short g_xh[NXEL_], g_xl[NXEL_];
__device__ unsigned short g_wtTh[WEL_], g_wtTl[WEL_];
__device__ unsigned short g_wpTh[WEL_], g_wpTl[WEL_];
__device__ unsigned short g_wgT[WEL_];
__device__ unsigned short g_wcT[WEL_];          // conv_out: [f][k] (unchanged)

__device__ __forceinline__ float b2f(unsigned short u) {
    union { unsigned int i; float f; } v; v.i = ((unsigned int)u) << 16; return v.f;
}
__device__ __forceinline__ unsigned short f2b(float f) {
    union { float f; unsigned int i; } v; v.f = f;
    unsigned int i = v.i;
    i += 0x7fffu + ((i >> 16) & 1u);   // RNE (finite only)
    return (unsigned short)(i >> 16);
}

typedef __attribute__((ext_vector_type(8))) short bf16x8;
typedef __attribute__((ext_vector_type(4))) float f32x4;

__device__ __forceinline__ f32x4 mfma16(bf16x8 a, bf16x8 b, f32x4 c) {
    return __builtin_amdgcn_mfma_f32_16x16x32_bf16(a, b, c, 0, 0, 0);
}

// ---------------------------------------------------------------------------
// prep_x: fp32 x -> bf16 hi/lo split
// ---------------------------------------------------------------------------
__global__ __launch_bounds__(256) void prep_x(const float* __restrict__ x)
{
    const int i = (blockIdx.x * 256 + threadIdx.x) * 4;
    if (i >= NXEL_) return;
    const float4 v = *(const float4*)(x + i);
    ushort4 hi, lo;
    hi.x = f2b(v.x); lo.x = f2b(v.x - b2f(hi.x));
    hi.y = f2b(v.y); lo.y = f2b(v.y - b2f(hi.y));
    hi.z = f2b(v.z); lo.z = f2b(v.z - b2f(hi.z));
    hi.w = f2b(v.w); lo.w = f2b(v.w - b2f(hi.w));
    *(ushort4*)(g_xh + i) = hi;
    *(ushort4*)(g_xl + i) = lo;
}

// ---------------------------------------------------------------------------
// prep_w: attn-conv weights -> chunk-major [72][128][32] bf16 (hi/lo for
// w_theta/w_phi); conv_out weights -> [f][k] (unchanged).
// ---------------------------------------------------------------------------
__global__ __launch_bounds__(256) void prep_w(
    const float* __restrict__ wt, const float* __restrict__ wp,
    const float* __restrict__ wg, const float* __restrict__ wc)
{
    const int i = blockIdx.x * 256 + threadIdx.x;
    if (i >= WEL_) return;
    {
        const int t  = i / (256 * 128);
        const int r  = i % (256 * 128);
        const int ci = r >> 7;
        const int f  = r & 127;
        const size_t d = (size_t)(t * 8 + (ci >> 5)) * 4096
                       + (size_t)f * 32 + (ci & 31);
        const float tv = wt[i];
        const unsigned short th = f2b(tv);
        g_wtTh[d] = th; g_wtTl[d] = f2b(tv - b2f(th));
        const float pv = wp[i];
        const unsigned short ph = f2b(pv);
        g_wpTh[d] = ph; g_wpTl[d] = f2b(pv - b2f(ph));
        g_wgT[d] = f2b(wg[i]);
    }
    {
        const int t  = i / (128 * 256);
        const int r  = i % (128 * 256);
        const int ci = r >> 8;
        const int f  = r & 255;
        g_wcT[(size_t)f * KWC_ + t * 128 + ci] = f2b(wc[i]);
    }
}

// ---------------------------------------------------------------------------
// conv3_mfma v2: LDS-staged implicit-GEMM 3x3 conv, 3 heads fused.
// (verified r4: dropped conv3 out of the top-5, was 243us global-read)
// ---------------------------------------------------------------------------
__global__ __launch_bounds__(512) void conv3_mfma()
{
    __shared__ __align__(16) unsigned short w_lds[5][128][40];   // 50 KB
    __shared__ __align__(16) unsigned short x_lds[64][2][40];    // 10 KB

    const int tid  = threadIdx.x;
    const int wv   = tid >> 6;
    const int lane = tid & 63;
    const int quad = lane >> 4;
    const int ll   = lane & 15;
    const int wp   = wv >> 2;          // pixel group 0..1
    const int wf   = wv & 3;           // filter group 0..3
    const int P0   = blockIdx.x * 64;
    const int fb   = wf * 32;

    // staging thread maps
    const int sxp = tid >> 3;          // x: pixel 0..63
    const int sxh = (tid >> 2) & 1;    // x: hi/lo
    const int sxc = (tid & 3) * 8;     // x: ch offset
    const int swf = tid >> 2;          // w: filter 0..127
    const int swc = (tid & 3) * 8;     // w: ch offset

    // x staging source pixel coords
    const int sp  = P0 + sxp;
    const int spb = sp / NPIX_;
    const int spl = sp % NPIX_;
    const int sph = spl / WW_;
    const int spw = spl % WW_;

    const bf16x8 ZV = {0,0,0,0,0,0,0,0};
    bf16x8 rx, rw0, rw1, rw2, rw3, rw4;

#define C3_STAGE_LOAD(s)                                                      \
    {                                                                         \
        const int t_ = (s) >> 3, kc_ = (s) & 7;                               \
        const int hh_ = sph + t_ / 3 - 1, ww_ = spw + t_ % 3 - 1;             \
        if (hh_ >= 0 && hh_ < HH_ && ww_ >= 0 && ww_ < WW_) {                 \
            const size_t src_ = ((size_t)spb * NPIX_ + hh_ * WW_ + ww_) * CIN_\
                                + kc_ * 32 + sxc;                             \
            rx = sxh ? *(const bf16x8*)(g_xl + src_)                          \
                     : *(const bf16x8*)(g_xh + src_);                         \
        } else rx = ZV;                                                       \
        const size_t ws_ = (size_t)(s) * 4096 + (size_t)swf * 32 + swc;       \
        rw0 = *(const bf16x8*)(g_wtTh + ws_);                                 \
        rw1 = *(const bf16x8*)(g_wtTl + ws_);                                 \
        rw2 = *(const bf16x8*)(g_wpTh + ws_);                                 \
        rw3 = *(const bf16x8*)(g_wpTl + ws_);                                 \
        rw4 = *(const bf16x8*)(g_wgT  + ws_);                                 \
    }

#define C3_STAGE_WRITE()                                                      \
    {                                                                         \
        *(bf16x8*)(&x_lds[sxp][sxh][sxc]) = rx;                               \
        *(bf16x8*)(&w_lds[0][swf][swc]) = rw0;                                \
        *(bf16x8*)(&w_lds[1][swf][swc]) = rw1;                                \
        *(bf16x8*)(&w_lds[2][swf][swc]) = rw2;                                \
        *(bf16x8*)(&w_lds[3][swf][swc]) = rw3;                                \
        *(bf16x8*)(&w_lds[4][swf][swc]) = rw4;                                \
    }

    f32x4 aT[2][2], aP[2][2], aG[2][2];   // [pt][ft]
    #pragma unroll
    for (int pt = 0; pt < 2; ++pt)
        #pragma unroll
        for (int ft = 0; ft < 2; ++ft) {
            aT[pt][ft] = (f32x4){0.f,0.f,0.f,0.f};
            aP[pt][ft] = (f32x4){0.f,0.f,0.f,0.f};
            aG[pt][ft] = (f32x4){0.f,0.f,0.f,0.f};
        }

    C3_STAGE_LOAD(0);
    C3_STAGE_WRITE();
    __syncthreads();

    for (int s = 0; s < 72; ++s) {
        const bool pf = (s + 1 < 72);
        if (pf) C3_STAGE_LOAD(s + 1);

        bf16x8 xa[2][2];   // [pt][hi/lo]
        #pragma unroll
        for (int pt = 0; pt < 2; ++pt) {
            const int px = wp * 32 + pt * 16 + ll;
            xa[pt][0] = *(const bf16x8*)(&x_lds[px][0][quad * 8]);
            xa[pt][1] = *(const bf16x8*)(&x_lds[px][1][quad * 8]);
        }
        #pragma unroll
        for (int ft = 0; ft < 2; ++ft) {
            const int f = fb + ft * 16 + ll;
            const bf16x8 tH = *(const bf16x8*)(&w_lds[0][f][quad * 8]);
            const bf16x8 tL = *(const bf16x8*)(&w_lds[1][f][quad * 8]);
            const bf16x8 pH = *(const bf16x8*)(&w_lds[2][f][quad * 8]);
            const bf16x8 pL = *(const bf16x8*)(&w_lds[3][f][quad * 8]);
            const bf16x8 gB = *(const bf16x8*)(&w_lds[4][f][quad * 8]);
            #pragma unroll
            for (int pt = 0; pt < 2; ++pt) {
                aT[pt][ft] = mfma16(xa[pt][0], tH, aT[pt][ft]);
                aT[pt][ft] = mfma16(xa[pt][0], tL, aT[pt][ft]);
                aT[pt][ft] = mfma16(xa[pt][1], tH, aT[pt][ft]);
                aP[pt][ft] = mfma16(xa[pt][0], pH, aP[pt][ft]);
                aP[pt][ft] = mfma16(xa[pt][0], pL, aP[pt][ft]);
                aP[pt][ft] = mfma16(xa[pt][1], pH, aP[pt][ft]);
                aG[pt][ft] = mfma16(xa[pt][0], gB, aG[pt][ft]);
            }
        }

        __syncthreads();               // all reads of this tile done
        if (pf) C3_STAGE_WRITE();      // vmcnt wait folds in here
        __syncthreads();               // next tile visible
    }

    #pragma unroll
    for (int pt = 0; pt < 2; ++pt)
        #pragma unroll
        for (int ft = 0; ft < 2; ++ft) {
            const int f = fb + ft * 16 + ll;
            #pragma unroll
            for (int r = 0; r < 4; ++r) {
                const size_t n = P0 + wp * 32 + pt * 16 + quad * 4 + r;
                g_theta[n * NF_ + f] = aT[pt][ft][r];
                g_phi  [n * NF_ + f] = aP[pt][ft][r];
                g_gv   [n * NF_ + f] = aG[pt][ft][r];
            }
        }
#undef C3_STAGE_LOAD
#undef C3_STAGE_WRITE
}

// ---------------------------------------------------------------------------
// prep_pack (r14, verified)
// ---------------------------------------------------------------------------
__global__ __launch_bounds__(256) void prep_pack()
{
    const int i = blockIdx.x * 256 + threadIdx.x;
    if (i >= NELEM_) return;
    const int n  = i >> 7;
    const int c  = i & 127;
    const int b  = n / NPIX_;
    const int nl = n % NPIX_;

    const float tv = g_theta[i];
    const unsigned short th = f2b(tv);
    g_th_hi[i] = th;
    g_th_lo[i] = f2b(tv - b2f(th));

    const float pv = g_phi[i];
    const int j  = nl * 128 + c;
    const int cp = j / NPIX_;
    const int mp = j % NPIX_;
    const unsigned short phh = f2b(pv);
    const size_t o = (size_t)b * (NPIX_ * NF_) + (size_t)mp * 128 + cp;
    g_phT_hi[o] = phh;
    g_phT_lo[o] = f2b(pv - b2f(phh));

    g_gT[(size_t)b * (NPIX_ * NF_) + (size_t)c * NPIX_ + nl] = f2b(g_gv[i]);
}

// ---------------------------------------------------------------------------
// attn_mfma v6: v5 staging pipeline + swapped-QK^T in-register softmax +
// KVS 8.  (resubmit of r5 — container infra failed twice, no verdict)
//
// v5 counters (239us): VALUBusy 29.7 vs MfmaUtil 14.8, bank-conflict 1.86e7
// -- the softmax's 32 shfl_xor/iter (ds_swizzle chains), 12 exps, and 8
// scalar conflicting P ds_write_b16 dominate. v6:
//  - S computed as mfma(K,theta) (same fragments, swapped args): output
//    [m][q], each lane owns ONE q-row -> row reduce = 7 in-lane fmax +
//    2 shfl (xor 16,32); mi/li are per-lane scalars; P-pack becomes 2
//    vectorized b64 writes (lane holds 4 consecutive m).
//  - rescale factor al broadcast through p_lds's unused col 32..39 tail
//    (LDS stays exactly 32768 B -> 5 blocks/CU capacity).
//  - KVS 4->8: 25 iters (half the barriers), grid 1600 -> ~16 resident
//    waves/CU. Total staged KV bytes invariant; merge reads 52 MB.
//  - blockIdx&15 -> (b,kvs): each XCD owns one kvs chunk (1.2 MB, L2-fit).
// ---------------------------------------------------------------------------
__global__ __launch_bounds__(256) void attn_mfma()
{
    __shared__ __align__(16) unsigned short kh_lds[KVB_][136];  // 8.7 KB
    __shared__ __align__(16) unsigned short kl_lds[KVB_][136];  // 8.7 KB
    __shared__ __align__(16) unsigned short v_lds[NF_][40];     // 10 KB
    // per-wave: cols 0..31 = P rows [q][m]; cols 32..39 of rows 0..3 = al[16]
    __shared__ __align__(16) short p_lds[4][16 * 40];           // 5.1 KB

    const int tid  = threadIdx.x;
    const int w    = tid >> 6;
    const int lane = tid & 63;
    const int quad = lane >> 4;
    const int ll   = lane & 15;

    const int cid = blockIdx.x & 15;        // (b,kvs): round-robin over XCDs
    const int qw  = blockIdx.x >> 4;        // 0..99
    const int b   = cid >> 3;
    const int kvs = cid & 7;
    const int R0  = b * NPIX_ + qw * 64;    // 64 Q rows per block
    const int m_start = kvs * MCHUNK_;      // within-batch m offset

    const unsigned short* phH = g_phT_hi + (size_t)b * (NPIX_ * NF_);
    const unsigned short* phL = g_phT_lo + (size_t)b * (NPIX_ * NF_);
    const unsigned short* gT  = g_gT    + (size_t)b * (NPIX_ * NF_);

    // theta fragments for this wave's 16 rows (used as the B operand:
    // lane ll -> col q=ll, k-slice quad*8 within each kk block)
    bf16x8 aH[4], aL[4];
    #pragma unroll
    for (int kk = 0; kk < 4; ++kk) {
        const size_t off = (size_t)(R0 + w * 16 + ll) * 128 + kk * 32 + quad * 8;
        aH[kk] = *(const bf16x8*)(g_th_hi + off);
        aL[kk] = *(const bf16x8*)(g_th_lo + off);
    }

    f32x4 acc[8];
    #pragma unroll
    for (int t = 0; t < 8; ++t) acc[t] = (f32x4){0.f, 0.f, 0.f, 0.f};
    float mi = -1e30f, li = 0.f;            // per-lane: q = ll

    const int kr0 = tid >> 4;            // K rows 0..15 (and +16)
    const int kc0 = (tid & 15) * 8;      // K col elems
    const int vr0 = tid >> 2;            // V rows 0..63 (and +64)
    const int vm0 = (tid & 3) * 8;       // V m elems

    bf16x8 skh0, skh1, skl0, skl1, sv0, sv1;

    {
        const int m0 = m_start;
        skh0 = *(const bf16x8*)(phH + (size_t)(m0 + kr0) * 128 + kc0);
        skh1 = *(const bf16x8*)(phH + (size_t)(m0 + kr0 + 16) * 128 + kc0);
        skl0 = *(const bf16x8*)(phL + (size_t)(m0 + kr0) * 128 + kc0);
        skl1 = *(const bf16x8*)(phL + (size_t)(m0 + kr0 + 16) * 128 + kc0);
        sv0  = *(const bf16x8*)(gT + (size_t)vr0 * NPIX_ + m0 + vm0);
        sv1  = *(const bf16x8*)(gT + (size_t)(vr0 + 64) * NPIX_ + m0 + vm0);
        *(bf16x8*)(&kh_lds[kr0][kc0])      = skh0;
        *(bf16x8*)(&kh_lds[kr0 + 16][kc0]) = skh1;
        *(bf16x8*)(&kl_lds[kr0][kc0])      = skl0;
        *(bf16x8*)(&kl_lds[kr0 + 16][kc0]) = skl1;
        *(bf16x8*)(&v_lds[vr0][vm0])       = sv0;
        *(bf16x8*)(&v_lds[vr0 + 64][vm0])  = sv1;
    }
    __syncthreads();

    short* pl = &p_lds[w][0];

    for (int it = 0; it < NIT_; ++it) {
        const bool pf = (it + 1 < NIT_);
        if (pf) {
            const int m0 = m_start + (it + 1) * KVB_;
            skh0 = *(const bf16x8*)(phH + (size_t)(m0 + kr0) * 128 + kc0);
            skh1 = *(const bf16x8*)(phH + (size_t)(m0 + kr0 + 16) * 128 + kc0);
            skl0 = *(const bf16x8*)(phL + (size_t)(m0 + kr0) * 128 + kc0);
            skl1 = *(const bf16x8*)(phL + (size_t)(m0 + kr0 + 16) * 128 + kc0);
            sv0  = *(const bf16x8*)(gT + (size_t)vr0 * NPIX_ + m0 + vm0);
            sv1  = *(const bf16x8*)(gT + (size_t)(vr0 + 64) * NPIX_ + m0 + vm0);
        }

        // ---- S = K * theta^T (swapped): s[mt][r] = S[m=mt*16+quad*4+r][q=ll]
        f32x4 s[2];
        #pragma unroll
        for (int mt = 0; mt < 2; ++mt) {
            f32x4 s0 = (f32x4){0.f,0.f,0.f,0.f};
            const int mrow = mt * 16 + ll;
            #pragma unroll
            for (int kk = 0; kk < 4; ++kk) {
                const bf16x8 bH = *(const bf16x8*)(&kh_lds[mrow][kk * 32 + quad * 8]);
                const bf16x8 bL = *(const bf16x8*)(&kl_lds[mrow][kk * 32 + quad * 8]);
                s0 = mfma16(bH, aH[kk], s0);
                s0 = mfma16(bL, aH[kk], s0);
                s0 = mfma16(bH, aL[kk], s0);
            }
            s[mt] = s0;
        }

        // ---- per-lane online softmax for q = ll ---------------------------
        float cm = fmaxf(fmaxf(fmaxf(s[0][0], s[0][1]), fmaxf(s[0][2], s[0][3])),
                         fmaxf(fmaxf(s[1][0], s[1][1]), fmaxf(s[1][2], s[1][3])));
        cm = fmaxf(cm, __shfl_xor(cm, 16));
        cm = fmaxf(cm, __shfl_xor(cm, 32));
        const float nm = fmaxf(mi, cm);
        const float al = __expf(mi - nm);
        mi = nm;
        float ssum = 0.f;
        #pragma unroll
        for (int mt = 0; mt < 2; ++mt)
            #pragma unroll
            for (int r = 0; r < 4; ++r) {
                const float e = __expf(s[mt][r] - nm);
                s[mt][r] = e; ssum += e;
            }
        ssum += __shfl_xor(ssum, 16);
        ssum += __shfl_xor(ssum, 32);
        li = li * al + ssum;

        // broadcast al (indexed by q) through the p_lds tail
        if (quad == 0)
            ((float*)(pl + (ll >> 2) * 40 + 32))[ll & 3] = al;

        // ---- P pack: lane writes 4 consecutive m per mt (b64 stores) ------
        #pragma unroll
        for (int mt = 0; mt < 2; ++mt)
            *(ushort4*)(pl + ll * 40 + mt * 16 + quad * 4) =
                make_ushort4(f2b(s[mt][0]), f2b(s[mt][1]),
                             f2b(s[mt][2]), f2b(s[mt][3]));

        // ---- rescale acc rows with their al -------------------------------
        {
            const float* alp = (const float*)(pl + quad * 40 + 32);
            #pragma unroll
            for (int r = 0; r < 4; ++r) {
                const float av = alp[r];
                #pragma unroll
                for (int t = 0; t < 8; ++t) acc[t][r] *= av;
            }
        }

        const bf16x8 pa = *(const bf16x8*)(pl + ll * 40 + quad * 8);

        // ---- PV: 8 channel-tiles, k=32 ------------------------------------
        #pragma unroll
        for (int ct = 0; ct < 8; ++ct) {
            const bf16x8 gb = *(const bf16x8*)(&v_lds[ct * 16 + ll][quad * 8]);
            acc[ct] = mfma16(pa, gb, acc[ct]);
        }

        __syncthreads();
        if (pf) {
            *(bf16x8*)(&kh_lds[kr0][kc0])      = skh0;
            *(bf16x8*)(&kh_lds[kr0 + 16][kc0]) = skh1;
            *(bf16x8*)(&kl_lds[kr0][kc0])      = skl0;
            *(bf16x8*)(&kl_lds[kr0 + 16][kc0]) = skl1;
            *(bf16x8*)(&v_lds[vr0][vm0])       = sv0;
            *(bf16x8*)(&v_lds[vr0 + 64][vm0])  = sv1;
        }
        __syncthreads();
    }

    const int row0 = R0 + w * 16;
    #pragma unroll
    for (int ct = 0; ct < 8; ++ct)
        #pragma unroll
        for (int r = 0; r < 4; ++r)
            g_po[((size_t)kvs * NTOK_ + row0 + quad * 4 + r) * NF_ + ct * 16 + ll]
                = acc[ct][r];
    if (quad == 0) {
        const size_t mlidx = ((size_t)kvs * NTOK_ + row0 + ll) * 2;
        g_pml[mlidx]     = mi;
        g_pml[mlidx + 1] = li;
    }
}

// ---------------------------------------------------------------------------
// merge_attn: combine KVS_ fp32 partials -> normalized bf16 g_aob
// ---------------------------------------------------------------------------
__global__ __launch_bounds__(256) void merge_attn()
{
    const int idx = blockIdx.x * 256 + threadIdx.x;   // NTOK_*16 threads
    const int row = idx >> 4;
    const int c0  = (idx & 15) * 8;

    float m[KVS_], l[KVS_];
    #pragma unroll
    for (int s = 0; s < KVS_; ++s) {
        const size_t mlidx = ((size_t)s * NTOK_ + row) * 2;
        m[s] = g_pml[mlidx];
        l[s] = g_pml[mlidx + 1];
    }
    float M = m[0];
    #pragma unroll
    for (int s = 1; s < KVS_; ++s) M = fmaxf(M, m[s]);
    float a[KVS_], L = 0.f;
    #pragma unroll
    for (int s = 0; s < KVS_; ++s) {
        a[s] = __expf(m[s] - M);
        L += a[s] * l[s];
    }
    const float inv = 1.f / L;

    float o[8];
    #pragma unroll
    for (int j = 0; j < 8; ++j) o[j] = 0.f;
    #pragma unroll
    for (int s = 0; s < KVS_; ++s) {
        const float* p = g_po + ((size_t)s * NTOK_ + row) * NF_ + c0;
        const float4 p0 = *(const float4*)(p);
        const float4 p1 = *(const float4*)(p + 4);
        o[0] += a[s] * p0.x; o[1] += a[s] * p0.y;
        o[2] += a[s] * p0.z; o[3] += a[s] * p0.w;
        o[4] += a[s] * p1.x; o[5] += a[s] * p1.y;
        o[6] += a[s] * p1.z; o[7] += a[s] * p1.w;
    }
    unsigned short tmp[8];
    #pragma unroll
    for (int j = 0; j < 8; ++j) tmp[j] = f2b(o[j] * inv);
    unsigned short* dst = g_aob + (size_t)row * NF_ + c0;
    *(ushort4*)(dst)     = make_ushort4(tmp[0], tmp[1], tmp[2], tmp[3]);
    *(ushort4*)(dst + 4) = make_ushort4(tmp[4], tmp[5], tmp[6], tmp[7]);
}

// ---------------------------------------------------------------------------
// conv_out_mfma: implicit-GEMM 3x3 conv (128->256, bf16) + fp32 residual
// ---------------------------------------------------------------------------
__global__ __launch_bounds__(256) void conv_out_mfma(
    const float* __restrict__ x, float* __restrict__ out)
{
    const int tid = threadIdx.x;
    const int w = tid >> 6, lane = tid & 63, quad = lane >> 4, ll = lane & 15;
    const int P0 = blockIdx.x * 32;
    const int fb = w * 64;

    int pb[2], ph[2], pw[2];
    #pragma unroll
    for (int pt = 0; pt < 2; ++pt) {
        const int p = P0 + pt * 16 + ll;
        pb[pt] = p / NPIX_;
        const int pl_ = p % NPIX_;
        ph[pt] = pl_ / WW_;
        pw[pt] = pl_ % WW_;
    }

    const bf16x8 ZV = {0,0,0,0,0,0,0,0};
    f32x4 acc[2][4];
    #pragma unroll
    for (int pt = 0; pt < 2; ++pt)
        #pragma unroll
        for (int ft = 0; ft < 4; ++ft) acc[pt][ft] = (f32x4){0.f,0.f,0.f,0.f};

    for (int t = 0; t < 9; ++t) {
        const int dh = t / 3 - 1, dw = t % 3 - 1;
        size_t abase[2]; bool av[2];
        #pragma unroll
        for (int pt = 0; pt < 2; ++pt) {
            const int hh = ph[pt] + dh, ww2 = pw[pt] + dw;
            av[pt] = (hh >= 0 && hh < HH_ && ww2 >= 0 && ww2 < WW_);
            abase[pt] = ((size_t)pb[pt] * NPIX_ + hh * WW_ + ww2) * NF_;
        }
        for (int kc = 0; kc < 4; ++kc) {
            const int ko = kc * 32 + quad * 8;
            bf16x8 a[2];
            #pragma unroll
            for (int pt = 0; pt < 2; ++pt)
                a[pt] = av[pt] ? *(const bf16x8*)(g_aob + abase[pt] + ko) : ZV;
            const int wk = t * 128 + ko;
            #pragma unroll
            for (int ft = 0; ft < 4; ++ft) {
                const bf16x8 bw = *(const bf16x8*)(
                    g_wcT + (size_t)(fb + ft * 16 + ll) * KWC_ + wk);
                #pragma unroll
                for (int pt = 0; pt < 2; ++pt)
                    acc[pt][ft] = mfma16(a[pt], bw, acc[pt][ft]);
            }
        }
    }

    #pragma unroll
    for (int pt = 0; pt < 2; ++pt)
        #pragma unroll
        for (int ft = 0; ft < 4; ++ft) {
            const int f = fb + ft * 16 + ll;
            #pragma unroll
            for (int r = 0; r < 4; ++r) {
                const size_t n = P0 + pt * 16 + quad * 4 + r;
                const size_t oi = n * CIN_ + f;
                out[oi] = x[oi] + acc[pt][ft][r];
            }
        }
}

// ---------------------------------------------------------------------------
extern "C" void kernel_launch(void* const* d_in, const int* in_sizes, int n_in,
                              void* d_out, int out_size, void* d_ws, size_t ws_size,
                              hipStream_t stream)
{
    const float* x  = (const float*)d_in[0];
    const float* wt = (const float*)d_in[1];
    const float* wp = (const float*)d_in[2];
    const float* wg = (const float*)d_in[3];
    const float* wc = (const float*)d_in[4];
    float* out = (float*)d_out;

    prep_x<<<NXEL_ / 4 / 256, 256, 0, stream>>>(x);
    prep_w<<<(WEL_ + 255) / 256, 256, 0, stream>>>(wt, wp, wg, wc);
    conv3_mfma<<<NTOK_ / 64, 512, 0, stream>>>();
    prep_pack<<<(NELEM_ + 255) / 256, 256, 0, stream>>>();
    attn_mfma<<<(NTOK_ / 64) * KVS_, 256, 0, stream>>>();
    merge_attn<<<NTOK_ * 16 / 256, 256, 0, stream>>>();
    conv_out_mfma<<<400, 256, 0, stream>>>(x, out);
}

// Round 7
// 376.046 us; speedup vs baseline: 3.0573x; 1.0810x over previous
//
#include <hip/hip_runtime.h>
#include <hip/hip_bf16.h>

#define HH_ 80
#define WW_ 80
#define CIN_ 256
#define NF_ 128
#define NPIX_ 6400
#define NTOK_ 12800
#define NELEM_ (NTOK_ * NF_)       // 1,638,400
#define NXEL_  (NTOK_ * CIN_)      // 3,276,800
#define KW_    2304                // 9*256  (conv3 K)
#define KWC_   1152                // 9*128  (conv_out K)
#define WEL_   294912

// attention tiling
#define KVS_    8                  // KV splits across blocks
#define KVB_    32                 // m per staged tile
#define MCHUNK_ 800                // NPIX_/KVS_
#define NIT_    25                 // MCHUNK_/KVB_

// fp32 conv outputs (consumed by prep_pack)
__device__ float g_theta[NELEM_];
__device__ float g_phi  [NELEM_];
__device__ float g_gv   [NELEM_];
// bf16 attention output (consumed by conv_out_mfma)
__device__ unsigned short g_aob[NELEM_];
// bf16 MFMA operands for attention
__device__ unsigned short g_th_hi[NELEM_], g_th_lo[NELEM_];
__device__ unsigned short g_phT_hi[NELEM_], g_phT_lo[NELEM_];
__device__ unsigned short g_gT[NELEM_];
// split-KV fp32 partials (unnormalized O, running m/l)
__device__ float g_po [KVS_ * NELEM_];          // 52 MB
__device__ float g_pml[KVS_ * NTOK_ * 2];
// bf16 hi/lo split of x, and transposed bf16 weights
// attn-conv weights: chunk-major [72 chunks][128 f][32 ch] (chunk = t*8+kc)
// conv_out weights:  chunk-major [36 chunks][256 f][32 ch] (chunk = t*4+kc)
__device__ unsigned short g_xh[NXEL_], g_xl[NXEL_];
__device__ unsigned short g_wtTh[WEL_], g_wtTl[WEL_];
__device__ unsigned short g_wpTh[WEL_], g_wpTl[WEL_];
__device__ unsigned short g_wgT[WEL_];
__device__ unsigned short g_wcT[WEL_];

__device__ __forceinline__ float b2f(unsigned short u) {
    union { unsigned int i; float f; } v; v.i = ((unsigned int)u) << 16; return v.f;
}
__device__ __forceinline__ unsigned short f2b(float f) {
    union { float f; unsigned int i; } v; v.f = f;
    unsigned int i = v.i;
    i += 0x7fffu + ((i >> 16) & 1u);   // RNE (finite only)
    return (unsigned short)(i >> 16);
}

typedef __attribute__((ext_vector_type(8))) short bf16x8;
typedef __attribute__((ext_vector_type(4))) float f32x4;

__device__ __forceinline__ f32x4 mfma16(bf16x8 a, bf16x8 b, f32x4 c) {
    return __builtin_amdgcn_mfma_f32_16x16x32_bf16(a, b, c, 0, 0, 0);
}

// ---------------------------------------------------------------------------
// prep_x: fp32 x -> bf16 hi/lo split
// ---------------------------------------------------------------------------
__global__ __launch_bounds__(256) void prep_x(const float* __restrict__ x)
{
    const int i = (blockIdx.x * 256 + threadIdx.x) * 4;
    if (i >= NXEL_) return;
    const float4 v = *(const float4*)(x + i);
    ushort4 hi, lo;
    hi.x = f2b(v.x); lo.x = f2b(v.x - b2f(hi.x));
    hi.y = f2b(v.y); lo.y = f2b(v.y - b2f(hi.y));
    hi.z = f2b(v.z); lo.z = f2b(v.z - b2f(hi.z));
    hi.w = f2b(v.w); lo.w = f2b(v.w - b2f(hi.w));
    *(ushort4*)(g_xh + i) = hi;
    *(ushort4*)(g_xl + i) = lo;
}

// ---------------------------------------------------------------------------
// prep_w: attn-conv weights -> chunk-major [72][128][32] bf16 (hi/lo for
// w_theta/w_phi); conv_out weights -> chunk-major [36][256][32].
// ---------------------------------------------------------------------------
__global__ __launch_bounds__(256) void prep_w(
    const float* __restrict__ wt, const float* __restrict__ wp,
    const float* __restrict__ wg, const float* __restrict__ wc)
{
    const int i = blockIdx.x * 256 + threadIdx.x;
    if (i >= WEL_) return;
    {
        const int t  = i / (256 * 128);
        const int r  = i % (256 * 128);
        const int ci = r >> 7;
        const int f  = r & 127;
        const size_t d = (size_t)(t * 8 + (ci >> 5)) * 4096
                       + (size_t)f * 32 + (ci & 31);
        const float tv = wt[i];
        const unsigned short th = f2b(tv);
        g_wtTh[d] = th; g_wtTl[d] = f2b(tv - b2f(th));
        const float pv = wp[i];
        const unsigned short ph = f2b(pv);
        g_wpTh[d] = ph; g_wpTl[d] = f2b(pv - b2f(ph));
        g_wgT[d] = f2b(wg[i]);
    }
    {
        const int t  = i / (128 * 256);
        const int r  = i % (128 * 256);
        const int ci = r >> 8;
        const int f  = r & 255;
        const size_t d = (size_t)(t * 4 + (ci >> 5)) * 8192
                       + (size_t)f * 32 + (ci & 31);
        g_wcT[d] = f2b(wc[i]);
    }
}

// ---------------------------------------------------------------------------
// conv3_mfma v2: LDS-staged implicit-GEMM 3x3 conv, 3 heads fused.
// (verified r4: dropped conv3 out of the top-5, was 243us global-read)
// ---------------------------------------------------------------------------
__global__ __launch_bounds__(512) void conv3_mfma()
{
    __shared__ __align__(16) unsigned short w_lds[5][128][40];   // 50 KB
    __shared__ __align__(16) unsigned short x_lds[64][2][40];    // 10 KB

    const int tid  = threadIdx.x;
    const int wv   = tid >> 6;
    const int lane = tid & 63;
    const int quad = lane >> 4;
    const int ll   = lane & 15;
    const int wp   = wv >> 2;          // pixel group 0..1
    const int wf   = wv & 3;           // filter group 0..3
    const int P0   = blockIdx.x * 64;
    const int fb   = wf * 32;

    // staging thread maps
    const int sxp = tid >> 3;          // x: pixel 0..63
    const int sxh = (tid >> 2) & 1;    // x: hi/lo
    const int sxc = (tid & 3) * 8;     // x: ch offset
    const int swf = tid >> 2;          // w: filter 0..127
    const int swc = (tid & 3) * 8;     // w: ch offset

    // x staging source pixel coords
    const int sp  = P0 + sxp;
    const int spb = sp / NPIX_;
    const int spl = sp % NPIX_;
    const int sph = spl / WW_;
    const int spw = spl % WW_;

    const bf16x8 ZV = {0,0,0,0,0,0,0,0};
    bf16x8 rx, rw0, rw1, rw2, rw3, rw4;

#define C3_STAGE_LOAD(s)                                                      \
    {                                                                         \
        const int t_ = (s) >> 3, kc_ = (s) & 7;                               \
        const int hh_ = sph + t_ / 3 - 1, ww_ = spw + t_ % 3 - 1;             \
        if (hh_ >= 0 && hh_ < HH_ && ww_ >= 0 && ww_ < WW_) {                 \
            const size_t src_ = ((size_t)spb * NPIX_ + hh_ * WW_ + ww_) * CIN_\
                                + kc_ * 32 + sxc;                             \
            rx = sxh ? *(const bf16x8*)(g_xl + src_)                          \
                     : *(const bf16x8*)(g_xh + src_);                         \
        } else rx = ZV;                                                       \
        const size_t ws_ = (size_t)(s) * 4096 + (size_t)swf * 32 + swc;       \
        rw0 = *(const bf16x8*)(g_wtTh + ws_);                                 \
        rw1 = *(const bf16x8*)(g_wtTl + ws_);                                 \
        rw2 = *(const bf16x8*)(g_wpTh + ws_);                                 \
        rw3 = *(const bf16x8*)(g_wpTl + ws_);                                 \
        rw4 = *(const bf16x8*)(g_wgT  + ws_);                                 \
    }

#define C3_STAGE_WRITE()                                                      \
    {                                                                         \
        *(bf16x8*)(&x_lds[sxp][sxh][sxc]) = rx;                               \
        *(bf16x8*)(&w_lds[0][swf][swc]) = rw0;                                \
        *(bf16x8*)(&w_lds[1][swf][swc]) = rw1;                                \
        *(bf16x8*)(&w_lds[2][swf][swc]) = rw2;                                \
        *(bf16x8*)(&w_lds[3][swf][swc]) = rw3;                                \
        *(bf16x8*)(&w_lds[4][swf][swc]) = rw4;                                \
    }

    f32x4 aT[2][2], aP[2][2], aG[2][2];   // [pt][ft]
    #pragma unroll
    for (int pt = 0; pt < 2; ++pt)
        #pragma unroll
        for (int ft = 0; ft < 2; ++ft) {
            aT[pt][ft] = (f32x4){0.f,0.f,0.f,0.f};
            aP[pt][ft] = (f32x4){0.f,0.f,0.f,0.f};
            aG[pt][ft] = (f32x4){0.f,0.f,0.f,0.f};
        }

    C3_STAGE_LOAD(0);
    C3_STAGE_WRITE();
    __syncthreads();

    for (int s = 0; s < 72; ++s) {
        const bool pf = (s + 1 < 72);
        if (pf) C3_STAGE_LOAD(s + 1);

        bf16x8 xa[2][2];   // [pt][hi/lo]
        #pragma unroll
        for (int pt = 0; pt < 2; ++pt) {
            const int px = wp * 32 + pt * 16 + ll;
            xa[pt][0] = *(const bf16x8*)(&x_lds[px][0][quad * 8]);
            xa[pt][1] = *(const bf16x8*)(&x_lds[px][1][quad * 8]);
        }
        #pragma unroll
        for (int ft = 0; ft < 2; ++ft) {
            const int f = fb + ft * 16 + ll;
            const bf16x8 tH = *(const bf16x8*)(&w_lds[0][f][quad * 8]);
            const bf16x8 tL = *(const bf16x8*)(&w_lds[1][f][quad * 8]);
            const bf16x8 pH = *(const bf16x8*)(&w_lds[2][f][quad * 8]);
            const bf16x8 pL = *(const bf16x8*)(&w_lds[3][f][quad * 8]);
            const bf16x8 gB = *(const bf16x8*)(&w_lds[4][f][quad * 8]);
            #pragma unroll
            for (int pt = 0; pt < 2; ++pt) {
                aT[pt][ft] = mfma16(xa[pt][0], tH, aT[pt][ft]);
                aT[pt][ft] = mfma16(xa[pt][0], tL, aT[pt][ft]);
                aT[pt][ft] = mfma16(xa[pt][1], tH, aT[pt][ft]);
                aP[pt][ft] = mfma16(xa[pt][0], pH, aP[pt][ft]);
                aP[pt][ft] = mfma16(xa[pt][0], pL, aP[pt][ft]);
                aP[pt][ft] = mfma16(xa[pt][1], pH, aP[pt][ft]);
                aG[pt][ft] = mfma16(xa[pt][0], gB, aG[pt][ft]);
            }
        }

        __syncthreads();               // all reads of this tile done
        if (pf) C3_STAGE_WRITE();      // vmcnt wait folds in here
        __syncthreads();               // next tile visible
    }

    #pragma unroll
    for (int pt = 0; pt < 2; ++pt)
        #pragma unroll
        for (int ft = 0; ft < 2; ++ft) {
            const int f = fb + ft * 16 + ll;
            #pragma unroll
            for (int r = 0; r < 4; ++r) {
                const size_t n = P0 + wp * 32 + pt * 16 + quad * 4 + r;
                g_theta[n * NF_ + f] = aT[pt][ft][r];
                g_phi  [n * NF_ + f] = aP[pt][ft][r];
                g_gv   [n * NF_ + f] = aG[pt][ft][r];
            }
        }
#undef C3_STAGE_LOAD
#undef C3_STAGE_WRITE
}

// ---------------------------------------------------------------------------
// prep_pack (r14, verified)
// ---------------------------------------------------------------------------
__global__ __launch_bounds__(256) void prep_pack()
{
    const int i = blockIdx.x * 256 + threadIdx.x;
    if (i >= NELEM_) return;
    const int n  = i >> 7;
    const int c  = i & 127;
    const int b  = n / NPIX_;
    const int nl = n % NPIX_;

    const float tv = g_theta[i];
    const unsigned short th = f2b(tv);
    g_th_hi[i] = th;
    g_th_lo[i] = f2b(tv - b2f(th));

    const float pv = g_phi[i];
    const int j  = nl * 128 + c;
    const int cp = j / NPIX_;
    const int mp = j % NPIX_;
    const unsigned short phh = f2b(pv);
    const size_t o = (size_t)b * (NPIX_ * NF_) + (size_t)mp * 128 + cp;
    g_phT_hi[o] = phh;
    g_phT_lo[o] = f2b(pv - b2f(phh));

    g_gT[(size_t)b * (NPIX_ * NF_) + (size_t)c * NPIX_ + nl] = f2b(g_gv[i]);
}

// ---------------------------------------------------------------------------
// attn_mfma v7: v6 + T12 cvt_pk P-pack + T13 defer-rescale.
//
// v6 counters (165us): VALUBusy 39.2 > MfmaUtil 22.3 -- VALU-issue bound.
// Remaining VALU per wave-iter: 8 exp, 8 manual f2b (~30 instr), 32 rescale
// muls. v7:
//  - P-pack via v_cvt_pk_bf16_f32 (HW RNE, 2 floats/instr): 4 asm ops
//    replace ~26 VALU instrs.
//  - defer-rescale (THR=4, wave-uniform __all): skip al broadcast + 32 acc
//    muls + li mul when no q-row max grows >4. P <= e^4 in fp32 accum;
//    split-KV merge algebra exact for any mi >= rowmax-4.
// ---------------------------------------------------------------------------
__global__ __launch_bounds__(256) void attn_mfma()
{
    __shared__ __align__(16) unsigned short kh_lds[KVB_][136];  // 8.7 KB
    __shared__ __align__(16) unsigned short kl_lds[KVB_][136];  // 8.7 KB
    __shared__ __align__(16) unsigned short v_lds[NF_][40];     // 10 KB
    // per-wave: cols 0..31 = P rows [q][m]; cols 32..39 of rows 0..3 = al[16]
    __shared__ __align__(16) short p_lds[4][16 * 40];           // 5.1 KB

    const int tid  = threadIdx.x;
    const int w    = tid >> 6;
    const int lane = tid & 63;
    const int quad = lane >> 4;
    const int ll   = lane & 15;

    const int cid = blockIdx.x & 15;        // (b,kvs): round-robin over XCDs
    const int qw  = blockIdx.x >> 4;        // 0..99
    const int b   = cid >> 3;
    const int kvs = cid & 7;
    const int R0  = b * NPIX_ + qw * 64;    // 64 Q rows per block
    const int m_start = kvs * MCHUNK_;      // within-batch m offset

    const unsigned short* phH = g_phT_hi + (size_t)b * (NPIX_ * NF_);
    const unsigned short* phL = g_phT_lo + (size_t)b * (NPIX_ * NF_);
    const unsigned short* gT  = g_gT    + (size_t)b * (NPIX_ * NF_);

    // theta fragments for this wave's 16 rows (used as the B operand:
    // lane ll -> col q=ll, k-slice quad*8 within each kk block)
    bf16x8 aH[4], aL[4];
    #pragma unroll
    for (int kk = 0; kk < 4; ++kk) {
        const size_t off = (size_t)(R0 + w * 16 + ll) * 128 + kk * 32 + quad * 8;
        aH[kk] = *(const bf16x8*)(g_th_hi + off);
        aL[kk] = *(const bf16x8*)(g_th_lo + off);
    }

    f32x4 acc[8];
    #pragma unroll
    for (int t = 0; t < 8; ++t) acc[t] = (f32x4){0.f, 0.f, 0.f, 0.f};
    float mi = -1e30f, li = 0.f;            // per-lane: q = ll

    const int kr0 = tid >> 4;            // K rows 0..15 (and +16)
    const int kc0 = (tid & 15) * 8;      // K col elems
    const int vr0 = tid >> 2;            // V rows 0..63 (and +64)
    const int vm0 = (tid & 3) * 8;       // V m elems

    bf16x8 skh0, skh1, skl0, skl1, sv0, sv1;

    {
        const int m0 = m_start;
        skh0 = *(const bf16x8*)(phH + (size_t)(m0 + kr0) * 128 + kc0);
        skh1 = *(const bf16x8*)(phH + (size_t)(m0 + kr0 + 16) * 128 + kc0);
        skl0 = *(const bf16x8*)(phL + (size_t)(m0 + kr0) * 128 + kc0);
        skl1 = *(const bf16x8*)(phL + (size_t)(m0 + kr0 + 16) * 128 + kc0);
        sv0  = *(const bf16x8*)(gT + (size_t)vr0 * NPIX_ + m0 + vm0);
        sv1  = *(const bf16x8*)(gT + (size_t)(vr0 + 64) * NPIX_ + m0 + vm0);
        *(bf16x8*)(&kh_lds[kr0][kc0])      = skh0;
        *(bf16x8*)(&kh_lds[kr0 + 16][kc0]) = skh1;
        *(bf16x8*)(&kl_lds[kr0][kc0])      = skl0;
        *(bf16x8*)(&kl_lds[kr0 + 16][kc0]) = skl1;
        *(bf16x8*)(&v_lds[vr0][vm0])       = sv0;
        *(bf16x8*)(&v_lds[vr0 + 64][vm0])  = sv1;
    }
    __syncthreads();

    short* pl = &p_lds[w][0];

    for (int it = 0; it < NIT_; ++it) {
        const bool pf = (it + 1 < NIT_);
        if (pf) {
            const int m0 = m_start + (it + 1) * KVB_;
            skh0 = *(const bf16x8*)(phH + (size_t)(m0 + kr0) * 128 + kc0);
            skh1 = *(const bf16x8*)(phH + (size_t)(m0 + kr0 + 16) * 128 + kc0);
            skl0 = *(const bf16x8*)(phL + (size_t)(m0 + kr0) * 128 + kc0);
            skl1 = *(const bf16x8*)(phL + (size_t)(m0 + kr0 + 16) * 128 + kc0);
            sv0  = *(const bf16x8*)(gT + (size_t)vr0 * NPIX_ + m0 + vm0);
            sv1  = *(const bf16x8*)(gT + (size_t)(vr0 + 64) * NPIX_ + m0 + vm0);
        }

        // ---- S = K * theta^T (swapped): s[mt][r] = S[m=mt*16+quad*4+r][q=ll]
        f32x4 s[2];
        #pragma unroll
        for (int mt = 0; mt < 2; ++mt) {
            f32x4 s0 = (f32x4){0.f,0.f,0.f,0.f};
            const int mrow = mt * 16 + ll;
            #pragma unroll
            for (int kk = 0; kk < 4; ++kk) {
                const bf16x8 bH = *(const bf16x8*)(&kh_lds[mrow][kk * 32 + quad * 8]);
                const bf16x8 bL = *(const bf16x8*)(&kl_lds[mrow][kk * 32 + quad * 8]);
                s0 = mfma16(bH, aH[kk], s0);
                s0 = mfma16(bL, aH[kk], s0);
                s0 = mfma16(bH, aL[kk], s0);
            }
            s[mt] = s0;
        }

        // ---- per-lane online softmax for q = ll ---------------------------
        float cm = fmaxf(fmaxf(fmaxf(s[0][0], s[0][1]), fmaxf(s[0][2], s[0][3])),
                         fmaxf(fmaxf(s[1][0], s[1][1]), fmaxf(s[1][2], s[1][3])));
        cm = fmaxf(cm, __shfl_xor(cm, 16));
        cm = fmaxf(cm, __shfl_xor(cm, 32));
        // defer-rescale (T13): wave-uniform skip when no q-row grows > THR
        const bool nog = __all(cm <= mi + 4.0f);
        if (!nog) {
            const float nm = fmaxf(mi, cm);
            const float al = __expf(mi - nm);
            mi = nm;
            li *= al;
            if (quad == 0)
                ((float*)(pl + (ll >> 2) * 40 + 32))[ll & 3] = al;
        }
        float ssum = 0.f;
        #pragma unroll
        for (int mt = 0; mt < 2; ++mt)
            #pragma unroll
            for (int r = 0; r < 4; ++r) {
                const float e = __expf(s[mt][r] - mi);
                s[mt][r] = e; ssum += e;
            }
        ssum += __shfl_xor(ssum, 16);
        ssum += __shfl_xor(ssum, 32);
        li += ssum;

        // ---- P pack via v_cvt_pk_bf16_f32 (T12): 2 uint stores ------------
        #pragma unroll
        for (int mt = 0; mt < 2; ++mt) {
            unsigned int c0_, c1_;
            asm("v_cvt_pk_bf16_f32 %0, %1, %2"
                : "=v"(c0_) : "v"(s[mt][0]), "v"(s[mt][1]));
            asm("v_cvt_pk_bf16_f32 %0, %1, %2"
                : "=v"(c1_) : "v"(s[mt][2]), "v"(s[mt][3]));
            *(uint2*)(pl + ll * 40 + mt * 16 + quad * 4) = make_uint2(c0_, c1_);
        }

        // ---- rescale acc rows with their al (skipped when deferred) -------
        if (!nog) {
            const float* alp = (const float*)(pl + quad * 40 + 32);
            #pragma unroll
            for (int r = 0; r < 4; ++r) {
                const float av = alp[r];
                #pragma unroll
                for (int t = 0; t < 8; ++t) acc[t][r] *= av;
            }
        }

        const bf16x8 pa = *(const bf16x8*)(pl + ll * 40 + quad * 8);

        // ---- PV: 8 channel-tiles, k=32 ------------------------------------
        #pragma unroll
        for (int ct = 0; ct < 8; ++ct) {
            const bf16x8 gb = *(const bf16x8*)(&v_lds[ct * 16 + ll][quad * 8]);
            acc[ct] = mfma16(pa, gb, acc[ct]);
        }

        __syncthreads();
        if (pf) {
            *(bf16x8*)(&kh_lds[kr0][kc0])      = skh0;
            *(bf16x8*)(&kh_lds[kr0 + 16][kc0]) = skh1;
            *(bf16x8*)(&kl_lds[kr0][kc0])      = skl0;
            *(bf16x8*)(&kl_lds[kr0 + 16][kc0]) = skl1;
            *(bf16x8*)(&v_lds[vr0][vm0])       = sv0;
            *(bf16x8*)(&v_lds[vr0 + 64][vm0])  = sv1;
        }
        __syncthreads();
    }

    const int row0 = R0 + w * 16;
    #pragma unroll
    for (int ct = 0; ct < 8; ++ct)
        #pragma unroll
        for (int r = 0; r < 4; ++r)
            g_po[((size_t)kvs * NTOK_ + row0 + quad * 4 + r) * NF_ + ct * 16 + ll]
                = acc[ct][r];
    if (quad == 0) {
        const size_t mlidx = ((size_t)kvs * NTOK_ + row0 + ll) * 2;
        g_pml[mlidx]     = mi;
        g_pml[mlidx + 1] = li;
    }
}

// ---------------------------------------------------------------------------
// merge_attn: combine KVS_ fp32 partials -> normalized bf16 g_aob
// ---------------------------------------------------------------------------
__global__ __launch_bounds__(256) void merge_attn()
{
    const int idx = blockIdx.x * 256 + threadIdx.x;   // NTOK_*16 threads
    const int row = idx >> 4;
    const int c0  = (idx & 15) * 8;

    float m[KVS_], l[KVS_];
    #pragma unroll
    for (int s = 0; s < KVS_; ++s) {
        const size_t mlidx = ((size_t)s * NTOK_ + row) * 2;
        m[s] = g_pml[mlidx];
        l[s] = g_pml[mlidx + 1];
    }
    float M = m[0];
    #pragma unroll
    for (int s = 1; s < KVS_; ++s) M = fmaxf(M, m[s]);
    float a[KVS_], L = 0.f;
    #pragma unroll
    for (int s = 0; s < KVS_; ++s) {
        a[s] = __expf(m[s] - M);
        L += a[s] * l[s];
    }
    const float inv = 1.f / L;

    float o[8];
    #pragma unroll
    for (int j = 0; j < 8; ++j) o[j] = 0.f;
    #pragma unroll
    for (int s = 0; s < KVS_; ++s) {
        const float* p = g_po + ((size_t)s * NTOK_ + row) * NF_ + c0;
        const float4 p0 = *(const float4*)(p);
        const float4 p1 = *(const float4*)(p + 4);
        o[0] += a[s] * p0.x; o[1] += a[s] * p0.y;
        o[2] += a[s] * p0.z; o[3] += a[s] * p0.w;
        o[4] += a[s] * p1.x; o[5] += a[s] * p1.y;
        o[6] += a[s] * p1.z; o[7] += a[s] * p1.w;
    }
    unsigned short tmp[8];
    #pragma unroll
    for (int j = 0; j < 8; ++j) tmp[j] = f2b(o[j] * inv);
    unsigned short* dst = g_aob + (size_t)row * NF_ + c0;
    *(ushort4*)(dst)     = make_ushort4(tmp[0], tmp[1], tmp[2], tmp[3]);
    *(ushort4*)(dst + 4) = make_ushort4(tmp[4], tmp[5], tmp[6], tmp[7]);
}

// ---------------------------------------------------------------------------
// conv_out_mfma v2: LDS-staged implicit-GEMM 3x3 conv (128->256, bf16) +
// fp32 residual. Same recipe as conv3 v2 / attn v5 (3rd application):
// block = 64 pix x 256 f, 512 thr (8 waves = 2 pix-grp x 4 filt-grp, wave
// tile 32x64). Per step (t,kc): stage 16 KB W (chunk-major [36][256][32])
// + 4 KB A into LDS, register prefetch one step ahead. Issued global bytes
// 354 MB -> 144 MB. LDS 25 KB.
// ---------------------------------------------------------------------------
__global__ __launch_bounds__(512) void conv_out_mfma(
    const float* __restrict__ x, float* __restrict__ out)
{
    __shared__ __align__(16) unsigned short w_lds[256][40];   // 20 KB
    __shared__ __align__(16) unsigned short a_lds[64][40];    // 5 KB

    const int tid  = threadIdx.x;
    const int wv   = tid >> 6;
    const int lane = tid & 63;
    const int quad = lane >> 4;
    const int ll   = lane & 15;
    const int wp   = wv >> 2;            // pixel group 0..1
    const int wf   = wv & 3;             // filter group 0..3 (64 f each)
    const int P0   = blockIdx.x * 64;
    const int fb   = wf * 64;

    // staging maps: W = 256 f x 32 ch (512 thr x 16 elem);
    //               A = 64 pix x 32 ch (256 thr x 8 elem)
    const int swf = tid >> 1;            // W: filter 0..255
    const int swc = (tid & 1) * 16;      // W: ch offset 0/16
    const int sap = tid >> 2;            // A: pixel idx (valid when tid<256)
    const int sac = (tid & 3) * 8;       // A: ch offset

    const int sp  = P0 + sap;
    const int spb = sp / NPIX_;
    const int spl = sp % NPIX_;
    const int sph = spl / WW_;
    const int spw = spl % WW_;

    const bf16x8 ZV = {0,0,0,0,0,0,0,0};
    bf16x8 ra, rwA, rwB;

#define CO_STAGE_LOAD(s)                                                      \
    {                                                                         \
        const int t_ = (s) >> 2, kc_ = (s) & 3;                               \
        if (tid < 256) {                                                      \
            const int hh_ = sph + t_ / 3 - 1, ww_ = spw + t_ % 3 - 1;         \
            if (hh_ >= 0 && hh_ < HH_ && ww_ >= 0 && ww_ < WW_) {             \
                const size_t src_ = ((size_t)spb * NPIX_ + hh_ * WW_ + ww_)   \
                                    * NF_ + kc_ * 32 + sac;                   \
                ra = *(const bf16x8*)(g_aob + src_);                          \
            } else ra = ZV;                                                   \
        }                                                                     \
        const size_t ws_ = (size_t)(s) * 8192 + (size_t)swf * 32 + swc;       \
        rwA = *(const bf16x8*)(g_wcT + ws_);                                  \
        rwB = *(const bf16x8*)(g_wcT + ws_ + 8);                              \
    }

#define CO_STAGE_WRITE()                                                      \
    {                                                                         \
        if (tid < 256) *(bf16x8*)(&a_lds[sap][sac]) = ra;                     \
        *(bf16x8*)(&w_lds[swf][swc])     = rwA;                               \
        *(bf16x8*)(&w_lds[swf][swc + 8]) = rwB;                               \
    }

    f32x4 acc[2][4];
    #pragma unroll
    for (int pt = 0; pt < 2; ++pt)
        #pragma unroll
        for (int ft = 0; ft < 4; ++ft) acc[pt][ft] = (f32x4){0.f,0.f,0.f,0.f};

    CO_STAGE_LOAD(0);
    CO_STAGE_WRITE();
    __syncthreads();

    for (int s = 0; s < 36; ++s) {
        const bool pf = (s + 1 < 36);
        if (pf) CO_STAGE_LOAD(s + 1);

        bf16x8 a[2];
        #pragma unroll
        for (int pt = 0; pt < 2; ++pt)
            a[pt] = *(const bf16x8*)(&a_lds[wp * 32 + pt * 16 + ll][quad * 8]);
        #pragma unroll
        for (int ft = 0; ft < 4; ++ft) {
            const bf16x8 bw = *(const bf16x8*)(&w_lds[fb + ft * 16 + ll][quad * 8]);
            #pragma unroll
            for (int pt = 0; pt < 2; ++pt)
                acc[pt][ft] = mfma16(a[pt], bw, acc[pt][ft]);
        }

        __syncthreads();
        if (pf) CO_STAGE_WRITE();
        __syncthreads();
    }

    #pragma unroll
    for (int pt = 0; pt < 2; ++pt)
        #pragma unroll
        for (int ft = 0; ft < 4; ++ft) {
            const int f = fb + ft * 16 + ll;
            #pragma unroll
            for (int r = 0; r < 4; ++r) {
                const size_t n = P0 + wp * 32 + pt * 16 + quad * 4 + r;
                const size_t oi = n * CIN_ + f;
                out[oi] = x[oi] + acc[pt][ft][r];
            }
        }
#undef CO_STAGE_LOAD
#undef CO_STAGE_WRITE
}

// ---------------------------------------------------------------------------
extern "C" void kernel_launch(void* const* d_in, const int* in_sizes, int n_in,
                              void* d_out, int out_size, void* d_ws, size_t ws_size,
                              hipStream_t stream)
{
    const float* x  = (const float*)d_in[0];
    const float* wt = (const float*)d_in[1];
    const float* wp = (const float*)d_in[2];
    const float* wg = (const float*)d_in[3];
    const float* wc = (const float*)d_in[4];
    float* out = (float*)d_out;

    prep_x<<<NXEL_ / 4 / 256, 256, 0, stream>>>(x);
    prep_w<<<(WEL_ + 255) / 256, 256, 0, stream>>>(wt, wp, wg, wc);
    conv3_mfma<<<NTOK_ / 64, 512, 0, stream>>>();
    prep_pack<<<(NELEM_ + 255) / 256, 256, 0, stream>>>();
    attn_mfma<<<(NTOK_ / 64) * KVS_, 256, 0, stream>>>();
    merge_attn<<<NTOK_ * 16 / 256, 256, 0, stream>>>();
    conv_out_mfma<<<NTOK_ / 64, 512, 0, stream>>>(x, out);
}